// Round 13
// baseline (146.314 us; speedup 1.0000x reference)
//
#include <hip/hip_runtime.h>
#include <math.h>

#define BB 4
#define LL 4096
#define DD 256
#define NROWS (BB*LL)      // 16384
#define CHUNK 32
#define NC (LL/CHUNK)      // 128
#define NB 8192            // counting-sort bins

typedef __bf16 bf16x8 __attribute__((ext_vector_type(8)));
typedef __bf16 bf16x4 __attribute__((ext_vector_type(4)));
typedef float floatx4 __attribute__((ext_vector_type(4)));

// ---------------- K1: u = {Wq^T w, Wk^T w} (u pre-zeroed) + split Wv (COALESCED, r9 layout) ----------------
// block g owns e-rows [16g,16g+16); thread d = column -> consecutive lanes =
// consecutive addresses on every load/store. 8192 atomicAdds total (negligible).
__global__ void k_prep(const float* __restrict__ Wq, const float* __restrict__ Wk,
                       const float* __restrict__ Wv, const float* __restrict__ w,
                       float* __restrict__ u,
                       __bf16* __restrict__ Wh, __bf16* __restrict__ Wl) {
    __shared__ float wl[16];
    int d = threadIdx.x;
    int e0 = blockIdx.x * 16;
    if (d < 16) wl[d] = w[e0 + d];
    __syncthreads();
    float aq = 0.f, ak = 0.f;
    #pragma unroll
    for (int j = 0; j < 16; ++j) {
        float we = wl[j];
        aq = fmaf(Wq[(size_t)(e0 + j)*DD + d], we, aq);
        ak = fmaf(Wk[(size_t)(e0 + j)*DD + d], we, ak);
        float wv = Wv[(size_t)(e0 + j)*DD + d];
        __bf16 h = (__bf16)wv;
        Wh[(size_t)(e0 + j)*DD + d] = h;
        Wl[(size_t)(e0 + j)*DD + d] = (__bf16)(wv - (float)h);
    }
    atomicAdd(&u[d], aq);
    atomicAdd(&u[DD + d], ak);
}

// ---------------- K2: V = x @ Wv^T via split-bf16 MFMA (r9 version: LDS A-staging) ----------------
__global__ void __launch_bounds__(256) k_gemm_mfma(
        const float* __restrict__ x,
        const __bf16* __restrict__ Wh, const __bf16* __restrict__ Wl,
        const float* __restrict__ u, const float* __restrict__ bmlp,
        float* __restrict__ V, float* __restrict__ a, float* __restrict__ c) {
    __shared__ __bf16 Ah[32*40];    // 2.5 KB
    __shared__ __bf16 Al[32*40];
    __shared__ float4 ul[128];      // uq (64 float4) + uk (64 float4)
    __shared__ float pros[512];
    const int tid = threadIdx.x;
    const int wave = tid >> 6, lane = tid & 63;
    const int rowBase = blockIdx.x * 32;
    const int quad = lane >> 4, l16 = lane & 15;
    const int srow = tid >> 3, skq = (tid & 7) * 4;   // staging: 8 thr/row

    if (tid < 128) ul[tid] = ((const float4*)u)[tid];

    floatx4 acc[2][4];
    #pragma unroll
    for (int rt = 0; rt < 2; ++rt)
        #pragma unroll
        for (int ct = 0; ct < 4; ++ct)
            acc[rt][ct] = (floatx4){0.f, 0.f, 0.f, 0.f};
    float aq = 0.f, ak = 0.f;

    for (int k0 = 0; k0 < DD; k0 += 32) {
        __syncthreads();
        float4 xv = *(const float4*)(x + (size_t)(rowBase + srow)*DD + k0 + skq);
        __bf16 h0 = (__bf16)xv.x, h1 = (__bf16)xv.y, h2 = (__bf16)xv.z, h3 = (__bf16)xv.w;
        bf16x4 hv = {h0, h1, h2, h3};
        bf16x4 lv = {(__bf16)(xv.x - (float)h0), (__bf16)(xv.y - (float)h1),
                     (__bf16)(xv.z - (float)h2), (__bf16)(xv.w - (float)h3)};
        *(bf16x4*)&Ah[srow*40 + skq] = hv;
        *(bf16x4*)&Al[srow*40 + skq] = lv;
        float4 q4 = ul[(k0 >> 2) + (tid & 7)];
        float4 k4 = ul[64 + (k0 >> 2) + (tid & 7)];
        aq = fmaf(xv.x, q4.x, fmaf(xv.y, q4.y, fmaf(xv.z, q4.z, fmaf(xv.w, q4.w, aq))));
        ak = fmaf(xv.x, k4.x, fmaf(xv.y, k4.y, fmaf(xv.z, k4.z, fmaf(xv.w, k4.w, ak))));
        __syncthreads();
        bf16x8 ah[2], al[2];
        #pragma unroll
        for (int rt = 0; rt < 2; ++rt) {
            int m = rt*16 + l16;
            ah[rt] = *(bf16x8*)&Ah[m*40 + quad*8];
            al[rt] = *(bf16x8*)&Al[m*40 + quad*8];
        }
        #pragma unroll
        for (int ct = 0; ct < 4; ++ct) {
            int n = wave*64 + ct*16 + l16;
            bf16x8 bh = *(const bf16x8*)(Wh + (size_t)n*DD + k0 + quad*8);
            bf16x8 bl = *(const bf16x8*)(Wl + (size_t)n*DD + k0 + quad*8);
            #pragma unroll
            for (int rt = 0; rt < 2; ++rt) {
                acc[rt][ct] = __builtin_amdgcn_mfma_f32_16x16x32_bf16(ah[rt], bh, acc[rt][ct], 0, 0, 0);
                acc[rt][ct] = __builtin_amdgcn_mfma_f32_16x16x32_bf16(ah[rt], bl, acc[rt][ct], 0, 0, 0);
                acc[rt][ct] = __builtin_amdgcn_mfma_f32_16x16x32_bf16(al[rt], bh, acc[rt][ct], 0, 0, 0);
            }
        }
    }
    #pragma unroll
    for (int rt = 0; rt < 2; ++rt)
        #pragma unroll
        for (int ct = 0; ct < 4; ++ct)
            #pragma unroll
            for (int i = 0; i < 4; ++i) {
                int row = rowBase + rt*16 + quad*4 + i;
                int col = wave*64 + ct*16 + l16;
                V[(size_t)row*DD + col] = acc[rt][ct][i];
            }
    __syncthreads();
    pros[tid] = aq;
    pros[256 + tid] = ak;
    __syncthreads();
    if (tid < 32) {
        float sa = 0.f, sc = 0.f;
        #pragma unroll
        for (int j = 0; j < 8; ++j) {
            sa += pros[tid*8 + j];
            sc += pros[256 + tid*8 + j];
        }
        a[rowBase + tid] = sa + bmlp[0];
        c[rowBase + tid] = sc;
    }
}

// ---------------- K3: counting sort + BIN-LEVEL SE (no rank-order SE scan) ----------------
__global__ void __launch_bounds__(1024) k_sortish(const float* __restrict__ c,
        int* __restrict__ binstart_g,       // [BB][NB+2]
        float* __restrict__ SEb,            // [BB][NB+2] exclusive bin e-prefix
        int* __restrict__ perm,
        float* __restrict__ c_sorted, float* __restrict__ e_sorted,
        float* __restrict__ hdr) {
    __shared__ int   hist[NB];     // 32 KB
    __shared__ float ehist[NB];    // 32 KB
    __shared__ float scrf[64];     // floats [0..32), ints at [32..64)
    int b = blockIdx.x, tid = threadIdx.x;
    int wave = tid >> 6, lane = tid & 63;
    int* scri = (int*)scrf;

    float4 cv = ((const float4*)(c + (size_t)b*LL))[tid];
    float cw[4] = {cv.x, cv.y, cv.z, cv.w};
    float mn = fminf(fminf(cw[0],cw[1]), fminf(cw[2],cw[3]));
    float mx = fmaxf(fmaxf(cw[0],cw[1]), fmaxf(cw[2],cw[3]));
    #pragma unroll
    for (int off = 32; off > 0; off >>= 1) {
        mn = fminf(mn, __shfl_down(mn, off));
        mx = fmaxf(mx, __shfl_down(mx, off));
    }
    if (lane == 0) { scrf[wave] = mn; scrf[32 + wave] = mx; }
    __syncthreads();
    if (wave == 0) {
        float m = (lane < 16) ? scrf[lane]      :  3.4e38f;
        float M = (lane < 16) ? scrf[32 + lane] : -3.4e38f;
        #pragma unroll
        for (int off = 32; off > 0; off >>= 1) {
            m = fminf(m, __shfl_down(m, off));
            M = fmaxf(M, __shfl_down(M, off));
        }
        if (lane == 0) { scrf[0] = m; scrf[1] = M; }
    }
    __syncthreads();
    float cmin = scrf[0], cmax = scrf[1];
    float scale = (float)NB / fmaxf(cmax - cmin, 1e-20f);
    float ev[4];
    #pragma unroll
    for (int u = 0; u < 4; ++u) ev[u] = expf(cmin - cw[u]);   // <= 1
    __syncthreads();

    ((int4*)hist)[tid]  = make_int4(0,0,0,0);
    ((int4*)hist)[tid + 1024] = make_int4(0,0,0,0);
    ((float4*)ehist)[tid] = make_float4(0.f,0.f,0.f,0.f);
    ((float4*)ehist)[tid + 1024] = make_float4(0.f,0.f,0.f,0.f);
    __syncthreads();

    int bins[4];
    #pragma unroll
    for (int u = 0; u < 4; ++u) {
        int bi = (int)((cw[u] - cmin) * scale);
        bi = bi < 0 ? 0 : (bi > NB-1 ? NB-1 : bi);
        bins[u] = bi;
        atomicAdd(&hist[bi], 1);
        atomicAdd(&ehist[bi], ev[u]);
    }
    __syncthreads();

    int loc[8]; int base = 0;
    float eloc[8]; float ebase = 0.f;
    #pragma unroll
    for (int j = 0; j < 8; ++j) {
        loc[j] = base;   base  += hist[tid*8 + j];
        eloc[j] = ebase; ebase += ehist[tid*8 + j];
    }
    int incl = base; float eincl = ebase;
    #pragma unroll
    for (int off = 1; off < 64; off <<= 1) {
        int t = __shfl_up(incl, off);
        float ft = __shfl_up(eincl, off);
        if (lane >= off) { incl += t; eincl += ft; }
    }
    if (lane == 63) { scri[32 + wave] = incl; scrf[wave] = eincl; }
    __syncthreads();
    if (wave == 0) {
        int v = (lane < 16) ? scri[32 + lane] : 0;
        float fv = (lane < 16) ? scrf[lane] : 0.f;
        int s = v; float fs = fv;
        #pragma unroll
        for (int off = 1; off < 16; off <<= 1) {
            int t = __shfl_up(s, off);
            float ft = __shfl_up(fs, off);
            if (lane >= off) { s += t; fs += ft; }
        }
        if (lane < 16) { scri[32 + lane] = s - v; scrf[lane] = fs - fv; }
    }
    __syncthreads();
    int thread_excl = (incl - base) + scri[32 + wave];
    float ethread_excl = (eincl - ebase) + scrf[wave];
    #pragma unroll
    for (int j = 0; j < 8; ++j) {
        int bs = thread_excl + loc[j];
        binstart_g[(size_t)b*(NB+2) + tid*8 + j] = bs;
        SEb[(size_t)b*(NB+2) + tid*8 + j] = ethread_excl + eloc[j];
        hist[tid*8 + j] = bs;                // LDS cursor copy for scatter
    }
    if (tid == 1023) {
        binstart_g[(size_t)b*(NB+2) + NB]     = LL;
        binstart_g[(size_t)b*(NB+2) + NB + 1] = LL;
        SEb[(size_t)b*(NB+2) + NB] = ethread_excl + ebase;   // total e
        hdr[b*2 + 0] = cmin;
        hdr[b*2 + 1] = scale;
    }
    __syncthreads();

    #pragma unroll
    for (int u = 0; u < 4; ++u) {
        int i = tid*4 + u;
        int r = atomicAdd(&hist[bins[u]], 1);
        perm[(size_t)b*LL + r] = i;
        c_sorted[(size_t)b*LL + r] = cw[u];
        e_sorted[(size_t)b*LL + r] = ev[u];
    }
}

// ---------------- K4: chunked exclusive prefix over V in rank order ----------------
__global__ void k_scan(const float* __restrict__ V, const int* __restrict__ perm,
        const float* __restrict__ e_sorted,
        float* __restrict__ Pl, float* __restrict__ Pel,
        float* __restrict__ Tp, float* __restrict__ Te) {
    int b = blockIdx.y, q = blockIdx.x;
    int d = threadIdx.x;
    __shared__ int pj[CHUNK];
    __shared__ float pe[CHUNK];
    if (d < CHUNK) {
        pj[d] = perm[(size_t)b*LL + q*CHUNK + d];
        pe[d] = e_sorted[(size_t)b*LL + q*CHUNK + d];
    }
    __syncthreads();
    float vr[CHUNK];
    #pragma unroll
    for (int r = 0; r < CHUNK; ++r)
        vr[r] = V[((size_t)b*LL + pj[r]) * DD + d];
    float acc = 0.f, acce = 0.f;
    size_t kb = (size_t)b*LL + (size_t)q*CHUNK;
    #pragma unroll
    for (int r = 0; r < CHUNK; ++r) {
        size_t o = (kb + r) * DD + d;
        Pl[o]  = acc;
        Pel[o] = acce;
        acc += vr[r];
        acce = fmaf(pe[r], vr[r], acce);
    }
    size_t to = ((size_t)b*NC + q) * DD + d;
    Tp[to] = acc;
    Te[to] = acce;
}

// ---------------- K5: chunk bases, parallel over (q, b) ----------------
__global__ void k_base(const float* __restrict__ Tp, const float* __restrict__ Te,
        float* __restrict__ baseP, float* __restrict__ basePe) {
    int q = blockIdx.x, b = blockIdx.y, d = threadIdx.x;
    float acc = 0.f, acce = 0.f;
    #pragma unroll 8
    for (int i = 0; i < q; ++i) {
        size_t ti = ((size_t)b*NC + i) * DD + d;
        acc += Tp[ti]; acce += Te[ti];
    }
    size_t o = ((size_t)b*(NC+1) + q) * DD + d;
    baseP[o] = acc; basePe[o] = acce;
}

// ---------------- K6: per-row output, O(1) bin lookup + exact boundary fix ----------------
__global__ void k_out(const float* __restrict__ a, const float* __restrict__ hdr,
                      const int* __restrict__ binstart, const float* __restrict__ SEb,
                      const float* __restrict__ c_sorted, const float* __restrict__ e_sorted,
                      const int* __restrict__ perm, const float* __restrict__ V,
                      const float* __restrict__ Pl, const float* __restrict__ Pel,
                      const float* __restrict__ baseP, const float* __restrict__ basePe,
                      float* __restrict__ out) {
    int row = blockIdx.x * 4 + (threadIdx.x >> 6);
    int lane = threadIdx.x & 63;
    int b = row >> 12;
    float ai = a[row];
    float cmin = hdr[b*2 + 0], scale = hdr[b*2 + 1];
    float t = (ai - cmin) * scale;
    int ib = t < 0.f ? 0 : (t >= (float)NB ? NB : (int)t);
    int k    = binstart[(size_t)b*(NB+2) + ib];
    int kend = binstart[(size_t)b*(NB+2) + ib + 1];
    float alpha = expf(cmin - ai);
    float Z = fmaf(alpha, (float)(LL - k), SEb[(size_t)b*(NB+2) + ib]);
    size_t db = (size_t)lane * 4;
    size_t totoff = ((size_t)b * (NC+1) + NC) * DD + db;
    float4 ptot  = *(const float4*)(baseP  + totoff);
    float4 pk, pek;
    if (k < LL) {
        int q = k >> 5;
        size_t po = ((size_t)b * LL + k) * DD + db;
        size_t bo = ((size_t)b * (NC+1) + q) * DD + db;
        float4 pl = *(const float4*)(Pl    + po);
        float4 bp = *(const float4*)(baseP + bo);
        float4 pe = *(const float4*)(Pel    + po);
        float4 be = *(const float4*)(basePe + bo);
        pk.x = pl.x + bp.x; pk.y = pl.y + bp.y; pk.z = pl.z + bp.z; pk.w = pl.w + bp.w;
        pek.x = pe.x + be.x; pek.y = pe.y + be.y; pek.z = pe.z + be.z; pek.w = pe.w + be.w;
    } else {
        pk = ptot;
        pek = *(const float4*)(basePe + totoff);
    }
    float4 num;
    num.x = fmaf(alpha, ptot.x - pk.x, pek.x);
    num.y = fmaf(alpha, ptot.y - pk.y, pek.y);
    num.z = fmaf(alpha, ptot.z - pk.z, pek.z);
    num.w = fmaf(alpha, ptot.w - pk.w, pek.w);
    for (int r = k; r < kend; ++r) {
        float cr = c_sorted[(size_t)b*LL + r];
        if (cr < ai) {
            float w = e_sorted[(size_t)b*LL + r] - alpha;
            int j = perm[(size_t)b*LL + r];
            float4 v = *(const float4*)(V + ((size_t)b*LL + j) * DD + db);
            num.x = fmaf(w, v.x, num.x);
            num.y = fmaf(w, v.y, num.y);
            num.z = fmaf(w, v.z, num.z);
            num.w = fmaf(w, v.w, num.w);
            Z += w;
        }
    }
    float invZ = 1.f / Z;
    float4 o;
    o.x = num.x * invZ; o.y = num.y * invZ; o.z = num.z * invZ; o.w = num.w * invZ;
    *(float4*)(out + (size_t)row * DD + db) = o;
}

extern "C" void kernel_launch(void* const* d_in, const int* in_sizes, int n_in,
                              void* d_out, int out_size, void* d_ws, size_t ws_size,
                              hipStream_t stream) {
    const float* x  = (const float*)d_in[0];
    const float* Wq = (const float*)d_in[1];
    const float* Wk = (const float*)d_in[2];
    const float* Wv = (const float*)d_in[3];
    const float* wm = (const float*)d_in[4];
    const float* bm = (const float*)d_in[5];
    float* out = (float*)d_out;
    float* ws = (float*)d_ws;

    size_t off = 0;
    auto alloc = [&](size_t n) {      // n in floats
        float* p = ws + off;
        off += (n + 255) & ~(size_t)255;
        return p;
    };
    float* u        = alloc(2*DD);
    float* a        = alloc(NROWS);
    float* c        = alloc(NROWS);
    float* c_sorted = alloc(NROWS);
    float* e_sorted = alloc(NROWS);
    float* SEb      = alloc((size_t)BB*(NB+2));
    int*   perm     = (int*)alloc(NROWS);
    int*   binstart = (int*)alloc((size_t)BB*(NB+2));
    float* hdr      = alloc(2*BB);
    float* V        = alloc((size_t)NROWS*DD);
    float* Pl       = alloc((size_t)NROWS*DD);
    float* Pel      = alloc((size_t)NROWS*DD);
    float* Tp       = alloc((size_t)BB*NC*DD);
    float* Te       = alloc((size_t)BB*NC*DD);
    float* baseP    = alloc((size_t)BB*(NC+1)*DD);
    float* basePe   = alloc((size_t)BB*(NC+1)*DD);
    __bf16* Wh      = (__bf16*)alloc((size_t)DD*DD/2);
    __bf16* Wl      = (__bf16*)alloc((size_t)DD*DD/2);

    hipMemsetAsync(u, 0, 2*DD*sizeof(float), stream);
    hipLaunchKernelGGL(k_prep, dim3(16), dim3(DD), 0, stream, Wq, Wk, Wv, wm, u, Wh, Wl);
    hipLaunchKernelGGL(k_gemm_mfma, dim3(NROWS/32), dim3(256), 0, stream,
                       x, Wh, Wl, u, bm, V, a, c);
    hipLaunchKernelGGL(k_sortish, dim3(BB), dim3(1024), 0, stream,
                       c, binstart, SEb, perm, c_sorted, e_sorted, hdr);
    hipLaunchKernelGGL(k_scan, dim3(NC, BB), dim3(DD), 0, stream, V, perm, e_sorted, Pl, Pel, Tp, Te);
    hipLaunchKernelGGL(k_base, dim3(NC+1, BB), dim3(DD), 0, stream, Tp, Te, baseP, basePe);
    hipLaunchKernelGGL(k_out, dim3(NROWS/4), dim3(256), 0, stream,
                       a, hdr, binstart, SEb, c_sorted, e_sorted, perm, V,
                       Pl, Pel, baseP, basePe, out);
}

// Round 14
// 137.263 us; speedup vs baseline: 1.0659x; 1.0659x over previous
//
#include <hip/hip_runtime.h>
#include <math.h>

#define BB 4
#define LL 4096
#define DD 256
#define NROWS (BB*LL)      // 16384
#define CHUNK 32
#define NC (LL/CHUNK)      // 128
#define NB 8192            // counting-sort bins

typedef __bf16 bf16x8 __attribute__((ext_vector_type(8)));
typedef __bf16 bf16x4 __attribute__((ext_vector_type(4)));
typedef float floatx4 __attribute__((ext_vector_type(4)));

// ---------------- K1: u = {Wq^T w, Wk^T w} (u pre-zeroed) + split Wv -> Wh+Wl ----------------
__global__ void k_prep(const float* __restrict__ Wq, const float* __restrict__ Wk,
                       const float* __restrict__ Wv, const float* __restrict__ w,
                       float* __restrict__ u,
                       __bf16* __restrict__ Wh, __bf16* __restrict__ Wl) {
    __shared__ float wl[16];
    int d = threadIdx.x;
    int e0 = blockIdx.x * 16;
    if (d < 16) wl[d] = w[e0 + d];
    __syncthreads();
    float aq = 0.f, ak = 0.f;
    #pragma unroll
    for (int j = 0; j < 16; ++j) {
        float we = wl[j];
        aq = fmaf(Wq[(size_t)(e0 + j)*DD + d], we, aq);
        ak = fmaf(Wk[(size_t)(e0 + j)*DD + d], we, ak);
        float wv = Wv[(size_t)(e0 + j)*DD + d];
        __bf16 h = (__bf16)wv;
        Wh[(size_t)(e0 + j)*DD + d] = h;
        Wl[(size_t)(e0 + j)*DD + d] = (__bf16)(wv - (float)h);
    }
    atomicAdd(&u[d], aq);
    atomicAdd(&u[DD + d], ak);
}

// ---------------- K2: V = x @ Wv^T via split-bf16 MFMA, fused split + a/c proj ----------------
__global__ void __launch_bounds__(256) k_gemm_mfma(
        const float* __restrict__ x,
        const __bf16* __restrict__ Wh, const __bf16* __restrict__ Wl,
        const float* __restrict__ u, const float* __restrict__ bmlp,
        float* __restrict__ V, float* __restrict__ a, float* __restrict__ c) {
    __shared__ __bf16 Ah[32*40];    // 2.5 KB
    __shared__ __bf16 Al[32*40];
    __shared__ float4 ul[128];      // uq (64 float4) + uk (64 float4)
    __shared__ float pros[512];
    const int tid = threadIdx.x;
    const int wave = tid >> 6, lane = tid & 63;
    const int rowBase = blockIdx.x * 32;
    const int quad = lane >> 4, l16 = lane & 15;
    const int srow = tid >> 3, skq = (tid & 7) * 4;   // staging: 8 thr/row

    if (tid < 128) ul[tid] = ((const float4*)u)[tid];

    floatx4 acc[2][4];
    #pragma unroll
    for (int rt = 0; rt < 2; ++rt)
        #pragma unroll
        for (int ct = 0; ct < 4; ++ct)
            acc[rt][ct] = (floatx4){0.f, 0.f, 0.f, 0.f};
    float aq = 0.f, ak = 0.f;

    for (int k0 = 0; k0 < DD; k0 += 32) {
        __syncthreads();
        float4 xv = *(const float4*)(x + (size_t)(rowBase + srow)*DD + k0 + skq);
        __bf16 h0 = (__bf16)xv.x, h1 = (__bf16)xv.y, h2 = (__bf16)xv.z, h3 = (__bf16)xv.w;
        bf16x4 hv = {h0, h1, h2, h3};
        bf16x4 lv = {(__bf16)(xv.x - (float)h0), (__bf16)(xv.y - (float)h1),
                     (__bf16)(xv.z - (float)h2), (__bf16)(xv.w - (float)h3)};
        *(bf16x4*)&Ah[srow*40 + skq] = hv;
        *(bf16x4*)&Al[srow*40 + skq] = lv;
        float4 q4 = ul[(k0 >> 2) + (tid & 7)];
        float4 k4 = ul[64 + (k0 >> 2) + (tid & 7)];
        aq = fmaf(xv.x, q4.x, fmaf(xv.y, q4.y, fmaf(xv.z, q4.z, fmaf(xv.w, q4.w, aq))));
        ak = fmaf(xv.x, k4.x, fmaf(xv.y, k4.y, fmaf(xv.z, k4.z, fmaf(xv.w, k4.w, ak))));
        __syncthreads();
        bf16x8 ah[2], al[2];
        #pragma unroll
        for (int rt = 0; rt < 2; ++rt) {
            int m = rt*16 + l16;
            ah[rt] = *(bf16x8*)&Ah[m*40 + quad*8];
            al[rt] = *(bf16x8*)&Al[m*40 + quad*8];
        }
        #pragma unroll
        for (int ct = 0; ct < 4; ++ct) {
            int n = wave*64 + ct*16 + l16;
            bf16x8 bh = *(const bf16x8*)(Wh + (size_t)n*DD + k0 + quad*8);
            bf16x8 bl = *(const bf16x8*)(Wl + (size_t)n*DD + k0 + quad*8);
            #pragma unroll
            for (int rt = 0; rt < 2; ++rt) {
                acc[rt][ct] = __builtin_amdgcn_mfma_f32_16x16x32_bf16(ah[rt], bh, acc[rt][ct], 0, 0, 0);
                acc[rt][ct] = __builtin_amdgcn_mfma_f32_16x16x32_bf16(ah[rt], bl, acc[rt][ct], 0, 0, 0);
                acc[rt][ct] = __builtin_amdgcn_mfma_f32_16x16x32_bf16(al[rt], bh, acc[rt][ct], 0, 0, 0);
            }
        }
    }
    #pragma unroll
    for (int rt = 0; rt < 2; ++rt)
        #pragma unroll
        for (int ct = 0; ct < 4; ++ct)
            #pragma unroll
            for (int i = 0; i < 4; ++i) {
                int row = rowBase + rt*16 + quad*4 + i;
                int col = wave*64 + ct*16 + l16;
                V[(size_t)row*DD + col] = acc[rt][ct][i];
            }
    // reduce projection partials: tid = srow*8 + kt
    __syncthreads();
    pros[tid] = aq;
    pros[256 + tid] = ak;
    __syncthreads();
    if (tid < 32) {
        float sa = 0.f, sc = 0.f;
        #pragma unroll
        for (int j = 0; j < 8; ++j) {
            sa += pros[tid*8 + j];
            sc += pros[256 + tid*8 + j];
        }
        a[rowBase + tid] = sa + bmlp[0];
        c[rowBase + tid] = sc;
    }
}

// ---------------- K3: counting sort by value-bin + SE prefix (r9 rank-SE version) ----------------
__global__ void __launch_bounds__(1024) k_sortish(const float* __restrict__ c,
        int* __restrict__ binstart_g, int* __restrict__ perm,
        float* __restrict__ c_sorted, float* __restrict__ e_sorted,
        float* __restrict__ SE, float* __restrict__ hdr) {
    __shared__ float cl[LL];
    __shared__ int   hist[NB];
    __shared__ float esl[LL];
    __shared__ float scrf[64];
    int b = blockIdx.x, tid = threadIdx.x;
    int wave = tid >> 6, lane = tid & 63;
    int* scri = (int*)scrf;

    float4 cv = ((const float4*)(c + (size_t)b*LL))[tid];
    ((float4*)cl)[tid] = cv;
    float cw[4] = {cv.x, cv.y, cv.z, cv.w};
    float mn = fminf(fminf(cw[0],cw[1]), fminf(cw[2],cw[3]));
    float mx = fmaxf(fmaxf(cw[0],cw[1]), fmaxf(cw[2],cw[3]));
    #pragma unroll
    for (int off = 32; off > 0; off >>= 1) {
        mn = fminf(mn, __shfl_down(mn, off));
        mx = fmaxf(mx, __shfl_down(mx, off));
    }
    if (lane == 0) { scrf[wave] = mn; scrf[32 + wave] = mx; }
    __syncthreads();
    if (wave == 0) {
        float m = (lane < 16) ? scrf[lane]      :  3.4e38f;
        float M = (lane < 16) ? scrf[32 + lane] : -3.4e38f;
        #pragma unroll
        for (int off = 32; off > 0; off >>= 1) {
            m = fminf(m, __shfl_down(m, off));
            M = fmaxf(M, __shfl_down(M, off));
        }
        if (lane == 0) { scrf[0] = m; scrf[1] = M; }
    }
    __syncthreads();
    float cmin = scrf[0], cmax = scrf[1];
    float scale = (float)NB / fmaxf(cmax - cmin, 1e-20f);
    __syncthreads();

    ((int4*)hist)[tid] = make_int4(0,0,0,0);
    ((int4*)hist)[tid + 1024] = make_int4(0,0,0,0);
    __syncthreads();

    int bins[4];
    #pragma unroll
    for (int u = 0; u < 4; ++u) {
        int bi = (int)((cw[u] - cmin) * scale);
        bi = bi < 0 ? 0 : (bi > NB-1 ? NB-1 : bi);
        bins[u] = bi;
        atomicAdd(&hist[bi], 1);
    }
    __syncthreads();

    int loc[8]; int base = 0;
    #pragma unroll
    for (int j = 0; j < 8; ++j) { loc[j] = base; base += hist[tid*8 + j]; }
    int incl = base;
    #pragma unroll
    for (int off = 1; off < 64; off <<= 1) {
        int t = __shfl_up(incl, off);
        if (lane >= off) incl += t;
    }
    if (lane == 63) scri[wave] = incl;
    __syncthreads();
    if (wave == 0) {
        int v = (lane < 16) ? scri[lane] : 0;
        int s = v;
        #pragma unroll
        for (int off = 1; off < 16; off <<= 1) {
            int t = __shfl_up(s, off);
            if (lane >= off) s += t;
        }
        if (lane < 16) scri[lane] = s - v;
    }
    __syncthreads();
    int thread_excl = (incl - base) + scri[wave];
    __syncthreads();
    #pragma unroll
    for (int j = 0; j < 8; ++j) {
        int bs = thread_excl + loc[j];
        binstart_g[(size_t)b*(NB+2) + tid*8 + j] = bs;
        hist[tid*8 + j] = bs;
    }
    if (tid == 0) {
        binstart_g[(size_t)b*(NB+2) + NB]     = LL;
        binstart_g[(size_t)b*(NB+2) + NB + 1] = LL;
        hdr[b*2 + 0] = cmin;
        hdr[b*2 + 1] = scale;
    }
    __syncthreads();

    #pragma unroll
    for (int u = 0; u < 4; ++u) {
        int i = tid*4 + u;
        int r = atomicAdd(&hist[bins[u]], 1);
        float e = expf(cmin - cw[u]);
        perm[(size_t)b*LL + r] = i;
        c_sorted[(size_t)b*LL + r] = cw[u];
        e_sorted[(size_t)b*LL + r] = e;
        esl[r] = e;
    }
    __syncthreads();

    float le[4]; float s0 = 0.f;
    #pragma unroll
    for (int u = 0; u < 4; ++u) { le[u] = s0; s0 += esl[tid*4 + u]; }
    float fincl = s0;
    #pragma unroll
    for (int off = 1; off < 64; off <<= 1) {
        float t = __shfl_up(fincl, off);
        if (lane >= off) fincl += t;
    }
    if (lane == 63) scrf[wave] = fincl;
    __syncthreads();
    if (wave == 0) {
        float v = (lane < 16) ? scrf[lane] : 0.f;
        float s = v;
        #pragma unroll
        for (int off = 1; off < 16; off <<= 1) {
            float t = __shfl_up(s, off);
            if (lane >= off) s += t;
        }
        if (lane < 16) scrf[lane] = s - v;
    }
    __syncthreads();
    float texcl = (fincl - s0) + scrf[wave];
    #pragma unroll
    for (int u = 0; u < 4; ++u)
        SE[(size_t)b*(LL+1) + tid*4 + u] = texcl + le[u];
    if (tid == 1023) SE[(size_t)b*(LL+1) + LL] = texcl + s0;
}

// ---------------- K4: chunked exclusive prefix over V in rank order ----------------
__global__ void k_scan(const float* __restrict__ V, const int* __restrict__ perm,
        const float* __restrict__ e_sorted,
        float* __restrict__ Pl, float* __restrict__ Pel,
        float* __restrict__ Tp, float* __restrict__ Te) {
    int b = blockIdx.y, q = blockIdx.x;
    int d = threadIdx.x;
    __shared__ int pj[CHUNK];
    __shared__ float pe[CHUNK];
    if (d < CHUNK) {
        pj[d] = perm[(size_t)b*LL + q*CHUNK + d];
        pe[d] = e_sorted[(size_t)b*LL + q*CHUNK + d];
    }
    __syncthreads();
    float vr[CHUNK];
    #pragma unroll
    for (int r = 0; r < CHUNK; ++r)
        vr[r] = V[((size_t)b*LL + pj[r]) * DD + d];
    float acc = 0.f, acce = 0.f;
    size_t kb = (size_t)b*LL + (size_t)q*CHUNK;
    #pragma unroll
    for (int r = 0; r < CHUNK; ++r) {
        size_t o = (kb + r) * DD + d;
        Pl[o]  = acc;
        Pel[o] = acce;
        acc += vr[r];
        acce = fmaf(pe[r], vr[r], acce);
    }
    size_t to = ((size_t)b*NC + q) * DD + d;
    Tp[to] = acc;
    Te[to] = acce;
}

// ---------------- K5: chunk bases, parallel over (q, b) ----------------
__global__ void k_base(const float* __restrict__ Tp, const float* __restrict__ Te,
        float* __restrict__ baseP, float* __restrict__ basePe) {
    int q = blockIdx.x, b = blockIdx.y, d = threadIdx.x;
    float acc = 0.f, acce = 0.f;
    #pragma unroll 8
    for (int i = 0; i < q; ++i) {
        size_t ti = ((size_t)b*NC + i) * DD + d;
        acc += Tp[ti]; acce += Te[ti];
    }
    size_t o = ((size_t)b*(NC+1) + q) * DD + d;
    baseP[o] = acc; basePe[o] = acce;
}

// ---------------- K6: per-row output, O(1) bin lookup + exact boundary fix ----------------
__global__ void k_out(const float* __restrict__ a, const float* __restrict__ hdr,
                      const int* __restrict__ binstart,
                      const float* __restrict__ c_sorted, const float* __restrict__ e_sorted,
                      const int* __restrict__ perm, const float* __restrict__ V,
                      const float* __restrict__ SE,
                      const float* __restrict__ Pl, const float* __restrict__ Pel,
                      const float* __restrict__ baseP, const float* __restrict__ basePe,
                      float* __restrict__ out) {
    int row = blockIdx.x * 4 + (threadIdx.x >> 6);
    int lane = threadIdx.x & 63;
    int b = row >> 12;
    float ai = a[row];
    float cmin = hdr[b*2 + 0], scale = hdr[b*2 + 1];
    float t = (ai - cmin) * scale;
    int ib = t < 0.f ? 0 : (t >= (float)NB ? NB : (int)t);
    int k    = binstart[(size_t)b*(NB+2) + ib];
    int kend = binstart[(size_t)b*(NB+2) + ib + 1];
    float alpha = expf(cmin - ai);
    float Z = fmaf(alpha, (float)(LL - k), SE[(size_t)b*(LL+1) + k]);
    size_t db = (size_t)lane * 4;
    size_t totoff = ((size_t)b * (NC+1) + NC) * DD + db;
    float4 ptot  = *(const float4*)(baseP  + totoff);
    float4 pk, pek;
    if (k < LL) {
        int q = k >> 5;
        size_t po = ((size_t)b * LL + k) * DD + db;
        size_t bo = ((size_t)b * (NC+1) + q) * DD + db;
        float4 pl = *(const float4*)(Pl    + po);
        float4 bp = *(const float4*)(baseP + bo);
        float4 pe = *(const float4*)(Pel    + po);
        float4 be = *(const float4*)(basePe + bo);
        pk.x = pl.x + bp.x; pk.y = pl.y + bp.y; pk.z = pl.z + bp.z; pk.w = pl.w + bp.w;
        pek.x = pe.x + be.x; pek.y = pe.y + be.y; pek.z = pe.z + be.z; pek.w = pe.w + be.w;
    } else {
        pk = ptot;
        pek = *(const float4*)(basePe + totoff);
    }
    float4 num;
    num.x = fmaf(alpha, ptot.x - pk.x, pek.x);
    num.y = fmaf(alpha, ptot.y - pk.y, pek.y);
    num.z = fmaf(alpha, ptot.z - pk.z, pek.z);
    num.w = fmaf(alpha, ptot.w - pk.w, pek.w);
    for (int r = k; r < kend; ++r) {
        float cr = c_sorted[(size_t)b*LL + r];
        if (cr < ai) {
            float w = e_sorted[(size_t)b*LL + r] - alpha;
            int j = perm[(size_t)b*LL + r];
            float4 v = *(const float4*)(V + ((size_t)b*LL + j) * DD + db);
            num.x = fmaf(w, v.x, num.x);
            num.y = fmaf(w, v.y, num.y);
            num.z = fmaf(w, v.z, num.z);
            num.w = fmaf(w, v.w, num.w);
            Z += w;
        }
    }
    float invZ = 1.f / Z;
    float4 o;
    o.x = num.x * invZ; o.y = num.y * invZ; o.z = num.z * invZ; o.w = num.w * invZ;
    *(float4*)(out + (size_t)row * DD + db) = o;
}

extern "C" void kernel_launch(void* const* d_in, const int* in_sizes, int n_in,
                              void* d_out, int out_size, void* d_ws, size_t ws_size,
                              hipStream_t stream) {
    const float* x  = (const float*)d_in[0];
    const float* Wq = (const float*)d_in[1];
    const float* Wk = (const float*)d_in[2];
    const float* Wv = (const float*)d_in[3];
    const float* wm = (const float*)d_in[4];
    const float* bm = (const float*)d_in[5];
    float* out = (float*)d_out;
    float* ws = (float*)d_ws;

    size_t off = 0;
    auto alloc = [&](size_t n) {      // n in floats
        float* p = ws + off;
        off += (n + 255) & ~(size_t)255;
        return p;
    };
    float* u        = alloc(2*DD);
    float* a        = alloc(NROWS);
    float* c        = alloc(NROWS);
    float* c_sorted = alloc(NROWS);
    float* e_sorted = alloc(NROWS);
    float* SE       = alloc((size_t)BB*(LL+1));
    int*   perm     = (int*)alloc(NROWS);
    int*   binstart = (int*)alloc((size_t)BB*(NB+2));
    float* hdr      = alloc(2*BB);
    float* V        = alloc((size_t)NROWS*DD);
    float* Pl       = alloc((size_t)NROWS*DD);
    float* Pel      = alloc((size_t)NROWS*DD);
    float* Tp       = alloc((size_t)BB*NC*DD);
    float* Te       = alloc((size_t)BB*NC*DD);
    float* baseP    = alloc((size_t)BB*(NC+1)*DD);
    float* basePe   = alloc((size_t)BB*(NC+1)*DD);
    __bf16* Wh      = (__bf16*)alloc((size_t)DD*DD/2);
    __bf16* Wl      = (__bf16*)alloc((size_t)DD*DD/2);

    hipMemsetAsync(u, 0, 2*DD*sizeof(float), stream);
    hipLaunchKernelGGL(k_prep, dim3(16), dim3(DD), 0, stream, Wq, Wk, Wv, wm, u, Wh, Wl);
    hipLaunchKernelGGL(k_gemm_mfma, dim3(NROWS/32), dim3(256), 0, stream,
                       x, Wh, Wl, u, bm, V, a, c);
    hipLaunchKernelGGL(k_sortish, dim3(BB), dim3(1024), 0, stream,
                       c, binstart, perm, c_sorted, e_sorted, SE, hdr);
    hipLaunchKernelGGL(k_scan, dim3(NC, BB), dim3(DD), 0, stream, V, perm, e_sorted, Pl, Pel, Tp, Te);
    hipLaunchKernelGGL(k_base, dim3(NC+1, BB), dim3(DD), 0, stream, Tp, Te, baseP, basePe);
    hipLaunchKernelGGL(k_out, dim3(NROWS/4), dim3(256), 0, stream,
                       a, hdr, binstart, c_sorted, e_sorted, perm, V,
                       SE, Pl, Pel, baseP, basePe, out);
}

// Round 15
// 135.448 us; speedup vs baseline: 1.0802x; 1.0134x over previous
//
#include <hip/hip_runtime.h>
#include <math.h>

#define BB 4
#define LL 4096
#define DD 256
#define NROWS (BB*LL)      // 16384
#define CHUNK 32
#define NC (LL/CHUNK)      // 128
#define NB 8192            // counting-sort bins

typedef __bf16 bf16x8 __attribute__((ext_vector_type(8)));
typedef __bf16 bf16x4 __attribute__((ext_vector_type(4)));
typedef float floatx4 __attribute__((ext_vector_type(4)));

// ---------------- K1: partial u = {Wq^T w, Wk^T w} (no atomics/memset) + split Wv ----------------
// block g writes u_part[g][0..256)=aq, [256..512)=ak; gemm reduces the 16 partials.
__global__ void k_prep(const float* __restrict__ Wq, const float* __restrict__ Wk,
                       const float* __restrict__ Wv, const float* __restrict__ w,
                       float* __restrict__ u_part,
                       __bf16* __restrict__ Wh, __bf16* __restrict__ Wl) {
    __shared__ float wl[16];
    int d = threadIdx.x;
    int e0 = blockIdx.x * 16;
    if (d < 16) wl[d] = w[e0 + d];
    __syncthreads();
    float aq = 0.f, ak = 0.f;
    #pragma unroll
    for (int j = 0; j < 16; ++j) {
        float we = wl[j];
        aq = fmaf(Wq[(size_t)(e0 + j)*DD + d], we, aq);
        ak = fmaf(Wk[(size_t)(e0 + j)*DD + d], we, ak);
        float wv = Wv[(size_t)(e0 + j)*DD + d];
        __bf16 h = (__bf16)wv;
        Wh[(size_t)(e0 + j)*DD + d] = h;
        Wl[(size_t)(e0 + j)*DD + d] = (__bf16)(wv - (float)h);
    }
    u_part[(size_t)blockIdx.x*512 + d]       = aq;
    u_part[(size_t)blockIdx.x*512 + DD + d]  = ak;
}

// ---------------- K2: V = x @ Wv^T via split-bf16 MFMA, fused split + a/c proj ----------------
// r14 structure + (a) u reduced from 16 partials at ul staging, (b) one-float4
// register prefetch of the next x tile (issued after 2nd barrier, overlaps MFMA).
__global__ void __launch_bounds__(256) k_gemm_mfma(
        const float* __restrict__ x,
        const __bf16* __restrict__ Wh, const __bf16* __restrict__ Wl,
        const float* __restrict__ u_part, const float* __restrict__ bmlp,
        float* __restrict__ V, float* __restrict__ a, float* __restrict__ c) {
    __shared__ __bf16 Ah[32*40];    // 2.5 KB
    __shared__ __bf16 Al[32*40];
    __shared__ float4 ul[128];      // uq (64 float4) + uk (64 float4)
    __shared__ float pros[512];
    const int tid = threadIdx.x;
    const int wave = tid >> 6, lane = tid & 63;
    const int rowBase = blockIdx.x * 32;
    const int quad = lane >> 4, l16 = lane & 15;
    const int srow = tid >> 3, skq = (tid & 7) * 4;   // staging: 8 thr/row

    if (tid < 128) {
        float4 s = make_float4(0.f, 0.f, 0.f, 0.f);
        #pragma unroll
        for (int g = 0; g < 16; ++g) {
            float4 p = *(const float4*)(u_part + (size_t)g*512 + tid*4);
            s.x += p.x; s.y += p.y; s.z += p.z; s.w += p.w;
        }
        ul[tid] = s;
    }

    floatx4 acc[2][4];
    #pragma unroll
    for (int rt = 0; rt < 2; ++rt)
        #pragma unroll
        for (int ct = 0; ct < 4; ++ct)
            acc[rt][ct] = (floatx4){0.f, 0.f, 0.f, 0.f};
    float aq = 0.f, ak = 0.f;

    const float* xrow = x + (size_t)(rowBase + srow)*DD + skq;
    float4 xv = *(const float4*)xrow;          // prefetch tile 0
    for (int k0 = 0; k0 < DD; k0 += 32) {
        __syncthreads();
        __bf16 h0 = (__bf16)xv.x, h1 = (__bf16)xv.y, h2 = (__bf16)xv.z, h3 = (__bf16)xv.w;
        bf16x4 hv = {h0, h1, h2, h3};
        bf16x4 lv = {(__bf16)(xv.x - (float)h0), (__bf16)(xv.y - (float)h1),
                     (__bf16)(xv.z - (float)h2), (__bf16)(xv.w - (float)h3)};
        *(bf16x4*)&Ah[srow*40 + skq] = hv;
        *(bf16x4*)&Al[srow*40 + skq] = lv;
        float4 q4 = ul[(k0 >> 2) + (tid & 7)];
        float4 k4 = ul[64 + (k0 >> 2) + (tid & 7)];
        aq = fmaf(xv.x, q4.x, fmaf(xv.y, q4.y, fmaf(xv.z, q4.z, fmaf(xv.w, q4.w, aq))));
        ak = fmaf(xv.x, k4.x, fmaf(xv.y, k4.y, fmaf(xv.z, k4.z, fmaf(xv.w, k4.w, ak))));
        __syncthreads();
        if (k0 < DD - 32) xv = *(const float4*)(xrow + k0 + 32);   // overlaps MFMAs below
        bf16x8 ah[2], al[2];
        #pragma unroll
        for (int rt = 0; rt < 2; ++rt) {
            int m = rt*16 + l16;
            ah[rt] = *(bf16x8*)&Ah[m*40 + quad*8];
            al[rt] = *(bf16x8*)&Al[m*40 + quad*8];
        }
        #pragma unroll
        for (int ct = 0; ct < 4; ++ct) {
            int n = wave*64 + ct*16 + l16;
            bf16x8 bh = *(const bf16x8*)(Wh + (size_t)n*DD + k0 + quad*8);
            bf16x8 bl = *(const bf16x8*)(Wl + (size_t)n*DD + k0 + quad*8);
            #pragma unroll
            for (int rt = 0; rt < 2; ++rt) {
                acc[rt][ct] = __builtin_amdgcn_mfma_f32_16x16x32_bf16(ah[rt], bh, acc[rt][ct], 0, 0, 0);
                acc[rt][ct] = __builtin_amdgcn_mfma_f32_16x16x32_bf16(ah[rt], bl, acc[rt][ct], 0, 0, 0);
                acc[rt][ct] = __builtin_amdgcn_mfma_f32_16x16x32_bf16(al[rt], bh, acc[rt][ct], 0, 0, 0);
            }
        }
    }
    #pragma unroll
    for (int rt = 0; rt < 2; ++rt)
        #pragma unroll
        for (int ct = 0; ct < 4; ++ct)
            #pragma unroll
            for (int i = 0; i < 4; ++i) {
                int row = rowBase + rt*16 + quad*4 + i;
                int col = wave*64 + ct*16 + l16;
                V[(size_t)row*DD + col] = acc[rt][ct][i];
            }
    // reduce projection partials: tid = srow*8 + kt
    __syncthreads();
    pros[tid] = aq;
    pros[256 + tid] = ak;
    __syncthreads();
    if (tid < 32) {
        float sa = 0.f, sc = 0.f;
        #pragma unroll
        for (int j = 0; j < 8; ++j) {
            sa += pros[tid*8 + j];
            sc += pros[256 + tid*8 + j];
        }
        a[rowBase + tid] = sa + bmlp[0];
        c[rowBase + tid] = sc;
    }
}

// ---------------- K3: counting sort by value-bin + SE prefix (r9 rank-SE, dead cl[] removed) ----------------
__global__ void __launch_bounds__(1024) k_sortish(const float* __restrict__ c,
        int* __restrict__ binstart_g, int* __restrict__ perm,
        float* __restrict__ c_sorted, float* __restrict__ e_sorted,
        float* __restrict__ SE, float* __restrict__ hdr) {
    __shared__ int   hist[NB];
    __shared__ float esl[LL];
    __shared__ float scrf[64];
    int b = blockIdx.x, tid = threadIdx.x;
    int wave = tid >> 6, lane = tid & 63;
    int* scri = (int*)scrf;

    float4 cv = ((const float4*)(c + (size_t)b*LL))[tid];
    float cw[4] = {cv.x, cv.y, cv.z, cv.w};
    float mn = fminf(fminf(cw[0],cw[1]), fminf(cw[2],cw[3]));
    float mx = fmaxf(fmaxf(cw[0],cw[1]), fmaxf(cw[2],cw[3]));
    #pragma unroll
    for (int off = 32; off > 0; off >>= 1) {
        mn = fminf(mn, __shfl_down(mn, off));
        mx = fmaxf(mx, __shfl_down(mx, off));
    }
    if (lane == 0) { scrf[wave] = mn; scrf[32 + wave] = mx; }
    __syncthreads();
    if (wave == 0) {
        float m = (lane < 16) ? scrf[lane]      :  3.4e38f;
        float M = (lane < 16) ? scrf[32 + lane] : -3.4e38f;
        #pragma unroll
        for (int off = 32; off > 0; off >>= 1) {
            m = fminf(m, __shfl_down(m, off));
            M = fmaxf(M, __shfl_down(M, off));
        }
        if (lane == 0) { scrf[0] = m; scrf[1] = M; }
    }
    __syncthreads();
    float cmin = scrf[0], cmax = scrf[1];
    float scale = (float)NB / fmaxf(cmax - cmin, 1e-20f);
    __syncthreads();

    ((int4*)hist)[tid] = make_int4(0,0,0,0);
    ((int4*)hist)[tid + 1024] = make_int4(0,0,0,0);
    __syncthreads();

    int bins[4];
    #pragma unroll
    for (int u = 0; u < 4; ++u) {
        int bi = (int)((cw[u] - cmin) * scale);
        bi = bi < 0 ? 0 : (bi > NB-1 ? NB-1 : bi);
        bins[u] = bi;
        atomicAdd(&hist[bi], 1);
    }
    __syncthreads();

    int loc[8]; int base = 0;
    #pragma unroll
    for (int j = 0; j < 8; ++j) { loc[j] = base; base += hist[tid*8 + j]; }
    int incl = base;
    #pragma unroll
    for (int off = 1; off < 64; off <<= 1) {
        int t = __shfl_up(incl, off);
        if (lane >= off) incl += t;
    }
    if (lane == 63) scri[wave] = incl;
    __syncthreads();
    if (wave == 0) {
        int v = (lane < 16) ? scri[lane] : 0;
        int s = v;
        #pragma unroll
        for (int off = 1; off < 16; off <<= 1) {
            int t = __shfl_up(s, off);
            if (lane >= off) s += t;
        }
        if (lane < 16) scri[lane] = s - v;
    }
    __syncthreads();
    int thread_excl = (incl - base) + scri[wave];
    __syncthreads();
    #pragma unroll
    for (int j = 0; j < 8; ++j) {
        int bs = thread_excl + loc[j];
        binstart_g[(size_t)b*(NB+2) + tid*8 + j] = bs;
        hist[tid*8 + j] = bs;
    }
    if (tid == 0) {
        binstart_g[(size_t)b*(NB+2) + NB]     = LL;
        binstart_g[(size_t)b*(NB+2) + NB + 1] = LL;
        hdr[b*2 + 0] = cmin;
        hdr[b*2 + 1] = scale;
    }
    __syncthreads();

    #pragma unroll
    for (int u = 0; u < 4; ++u) {
        int i = tid*4 + u;
        int r = atomicAdd(&hist[bins[u]], 1);
        float e = expf(cmin - cw[u]);
        perm[(size_t)b*LL + r] = i;
        c_sorted[(size_t)b*LL + r] = cw[u];
        e_sorted[(size_t)b*LL + r] = e;
        esl[r] = e;
    }
    __syncthreads();

    float le[4]; float s0 = 0.f;
    #pragma unroll
    for (int u = 0; u < 4; ++u) { le[u] = s0; s0 += esl[tid*4 + u]; }
    float fincl = s0;
    #pragma unroll
    for (int off = 1; off < 64; off <<= 1) {
        float t = __shfl_up(fincl, off);
        if (lane >= off) fincl += t;
    }
    if (lane == 63) scrf[wave] = fincl;
    __syncthreads();
    if (wave == 0) {
        float v = (lane < 16) ? scrf[lane] : 0.f;
        float s = v;
        #pragma unroll
        for (int off = 1; off < 16; off <<= 1) {
            float t = __shfl_up(s, off);
            if (lane >= off) s += t;
        }
        if (lane < 16) scrf[lane] = s - v;
    }
    __syncthreads();
    float texcl = (fincl - s0) + scrf[wave];
    #pragma unroll
    for (int u = 0; u < 4; ++u)
        SE[(size_t)b*(LL+1) + tid*4 + u] = texcl + le[u];
    if (tid == 1023) SE[(size_t)b*(LL+1) + LL] = texcl + s0;
}

// ---------------- K4: chunked exclusive prefix over V in rank order ----------------
__global__ void k_scan(const float* __restrict__ V, const int* __restrict__ perm,
        const float* __restrict__ e_sorted,
        float* __restrict__ Pl, float* __restrict__ Pel,
        float* __restrict__ Tp, float* __restrict__ Te) {
    int b = blockIdx.y, q = blockIdx.x;
    int d = threadIdx.x;
    __shared__ int pj[CHUNK];
    __shared__ float pe[CHUNK];
    if (d < CHUNK) {
        pj[d] = perm[(size_t)b*LL + q*CHUNK + d];
        pe[d] = e_sorted[(size_t)b*LL + q*CHUNK + d];
    }
    __syncthreads();
    float vr[CHUNK];
    #pragma unroll
    for (int r = 0; r < CHUNK; ++r)
        vr[r] = V[((size_t)b*LL + pj[r]) * DD + d];
    float acc = 0.f, acce = 0.f;
    size_t kb = (size_t)b*LL + (size_t)q*CHUNK;
    #pragma unroll
    for (int r = 0; r < CHUNK; ++r) {
        size_t o = (kb + r) * DD + d;
        Pl[o]  = acc;
        Pel[o] = acce;
        acc += vr[r];
        acce = fmaf(pe[r], vr[r], acce);
    }
    size_t to = ((size_t)b*NC + q) * DD + d;
    Tp[to] = acc;
    Te[to] = acce;
}

// ---------------- K5: chunk bases, parallel over (q, b) ----------------
__global__ void k_base(const float* __restrict__ Tp, const float* __restrict__ Te,
        float* __restrict__ baseP, float* __restrict__ basePe) {
    int q = blockIdx.x, b = blockIdx.y, d = threadIdx.x;
    float acc = 0.f, acce = 0.f;
    #pragma unroll 8
    for (int i = 0; i < q; ++i) {
        size_t ti = ((size_t)b*NC + i) * DD + d;
        acc += Tp[ti]; acce += Te[ti];
    }
    size_t o = ((size_t)b*(NC+1) + q) * DD + d;
    baseP[o] = acc; basePe[o] = acce;
}

// ---------------- K6: per-row output, O(1) bin lookup + exact boundary fix ----------------
__global__ void k_out(const float* __restrict__ a, const float* __restrict__ hdr,
                      const int* __restrict__ binstart,
                      const float* __restrict__ c_sorted, const float* __restrict__ e_sorted,
                      const int* __restrict__ perm, const float* __restrict__ V,
                      const float* __restrict__ SE,
                      const float* __restrict__ Pl, const float* __restrict__ Pel,
                      const float* __restrict__ baseP, const float* __restrict__ basePe,
                      float* __restrict__ out) {
    int row = blockIdx.x * 4 + (threadIdx.x >> 6);
    int lane = threadIdx.x & 63;
    int b = row >> 12;
    float ai = a[row];
    float cmin = hdr[b*2 + 0], scale = hdr[b*2 + 1];
    float t = (ai - cmin) * scale;
    int ib = t < 0.f ? 0 : (t >= (float)NB ? NB : (int)t);
    int k    = binstart[(size_t)b*(NB+2) + ib];
    int kend = binstart[(size_t)b*(NB+2) + ib + 1];
    float alpha = expf(cmin - ai);
    float Z = fmaf(alpha, (float)(LL - k), SE[(size_t)b*(LL+1) + k]);
    size_t db = (size_t)lane * 4;
    size_t totoff = ((size_t)b * (NC+1) + NC) * DD + db;
    float4 ptot  = *(const float4*)(baseP  + totoff);
    float4 pk, pek;
    if (k < LL) {
        int q = k >> 5;
        size_t po = ((size_t)b * LL + k) * DD + db;
        size_t bo = ((size_t)b * (NC+1) + q) * DD + db;
        float4 pl = *(const float4*)(Pl    + po);
        float4 bp = *(const float4*)(baseP + bo);
        float4 pe = *(const float4*)(Pel    + po);
        float4 be = *(const float4*)(basePe + bo);
        pk.x = pl.x + bp.x; pk.y = pl.y + bp.y; pk.z = pl.z + bp.z; pk.w = pl.w + bp.w;
        pek.x = pe.x + be.x; pek.y = pe.y + be.y; pek.z = pe.z + be.z; pek.w = pe.w + be.w;
    } else {
        pk = ptot;
        pek = *(const float4*)(basePe + totoff);
    }
    float4 num;
    num.x = fmaf(alpha, ptot.x - pk.x, pek.x);
    num.y = fmaf(alpha, ptot.y - pk.y, pek.y);
    num.z = fmaf(alpha, ptot.z - pk.z, pek.z);
    num.w = fmaf(alpha, ptot.w - pk.w, pek.w);
    for (int r = k; r < kend; ++r) {
        float cr = c_sorted[(size_t)b*LL + r];
        if (cr < ai) {
            float w = e_sorted[(size_t)b*LL + r] - alpha;
            int j = perm[(size_t)b*LL + r];
            float4 v = *(const float4*)(V + ((size_t)b*LL + j) * DD + db);
            num.x = fmaf(w, v.x, num.x);
            num.y = fmaf(w, v.y, num.y);
            num.z = fmaf(w, v.z, num.z);
            num.w = fmaf(w, v.w, num.w);
            Z += w;
        }
    }
    float invZ = 1.f / Z;
    float4 o;
    o.x = num.x * invZ; o.y = num.y * invZ; o.z = num.z * invZ; o.w = num.w * invZ;
    *(float4*)(out + (size_t)row * DD + db) = o;
}

extern "C" void kernel_launch(void* const* d_in, const int* in_sizes, int n_in,
                              void* d_out, int out_size, void* d_ws, size_t ws_size,
                              hipStream_t stream) {
    const float* x  = (const float*)d_in[0];
    const float* Wq = (const float*)d_in[1];
    const float* Wk = (const float*)d_in[2];
    const float* Wv = (const float*)d_in[3];
    const float* wm = (const float*)d_in[4];
    const float* bm = (const float*)d_in[5];
    float* out = (float*)d_out;
    float* ws = (float*)d_ws;

    size_t off = 0;
    auto alloc = [&](size_t n) {      // n in floats
        float* p = ws + off;
        off += (n + 255) & ~(size_t)255;
        return p;
    };
    float* u_part   = alloc(16*512);
    float* a        = alloc(NROWS);
    float* c        = alloc(NROWS);
    float* c_sorted = alloc(NROWS);
    float* e_sorted = alloc(NROWS);
    float* SE       = alloc((size_t)BB*(LL+1));
    int*   perm     = (int*)alloc(NROWS);
    int*   binstart = (int*)alloc((size_t)BB*(NB+2));
    float* hdr      = alloc(2*BB);
    float* V        = alloc((size_t)NROWS*DD);
    float* Pl       = alloc((size_t)NROWS*DD);
    float* Pel      = alloc((size_t)NROWS*DD);
    float* Tp       = alloc((size_t)BB*NC*DD);
    float* Te       = alloc((size_t)BB*NC*DD);
    float* baseP    = alloc((size_t)BB*(NC+1)*DD);
    float* basePe   = alloc((size_t)BB*(NC+1)*DD);
    __bf16* Wh      = (__bf16*)alloc((size_t)DD*DD/2);
    __bf16* Wl      = (__bf16*)alloc((size_t)DD*DD/2);

    hipLaunchKernelGGL(k_prep, dim3(16), dim3(DD), 0, stream, Wq, Wk, Wv, wm, u_part, Wh, Wl);
    hipLaunchKernelGGL(k_gemm_mfma, dim3(NROWS/32), dim3(256), 0, stream,
                       x, Wh, Wl, u_part, bm, V, a, c);
    hipLaunchKernelGGL(k_sortish, dim3(BB), dim3(1024), 0, stream,
                       c, binstart, perm, c_sorted, e_sorted, SE, hdr);
    hipLaunchKernelGGL(k_scan, dim3(NC, BB), dim3(DD), 0, stream, V, perm, e_sorted, Pl, Pel, Tp, Te);
    hipLaunchKernelGGL(k_base, dim3(NC+1, BB), dim3(DD), 0, stream, Tp, Te, baseP, basePe);
    hipLaunchKernelGGL(k_out, dim3(NROWS/4), dim3(256), 0, stream,
                       a, hdr, binstart, c_sorted, e_sorted, perm, V,
                       SE, Pl, Pel, baseP, basePe, out);
}

// Round 16
// 135.397 us; speedup vs baseline: 1.0806x; 1.0004x over previous
//
#include <hip/hip_runtime.h>
#include <math.h>

#define BB 4
#define LL 4096
#define DD 256
#define NROWS (BB*LL)      // 16384
#define CHUNK 32
#define NC (LL/CHUNK)      // 128
#define NB 8192            // counting-sort bins

typedef __bf16 bf16x8 __attribute__((ext_vector_type(8)));
typedef __bf16 bf16x4 __attribute__((ext_vector_type(4)));
typedef float floatx4 __attribute__((ext_vector_type(4)));

// ---------------- K1: partial u = {Wq^T w, Wk^T w} (no atomics/memset) + split Wv ----------------
__global__ void k_prep(const float* __restrict__ Wq, const float* __restrict__ Wk,
                       const float* __restrict__ Wv, const float* __restrict__ w,
                       float* __restrict__ u_part,
                       __bf16* __restrict__ Wh, __bf16* __restrict__ Wl) {
    __shared__ float wl[16];
    int d = threadIdx.x;
    int e0 = blockIdx.x * 16;
    if (d < 16) wl[d] = w[e0 + d];
    __syncthreads();
    float aq = 0.f, ak = 0.f;
    #pragma unroll
    for (int j = 0; j < 16; ++j) {
        float we = wl[j];
        aq = fmaf(Wq[(size_t)(e0 + j)*DD + d], we, aq);
        ak = fmaf(Wk[(size_t)(e0 + j)*DD + d], we, ak);
        float wv = Wv[(size_t)(e0 + j)*DD + d];
        __bf16 h = (__bf16)wv;
        Wh[(size_t)(e0 + j)*DD + d] = h;
        Wl[(size_t)(e0 + j)*DD + d] = (__bf16)(wv - (float)h);
    }
    u_part[(size_t)blockIdx.x*512 + d]       = aq;
    u_part[(size_t)blockIdx.x*512 + DD + d]  = ak;
}

// ---------------- K2: V = x @ Wv^T via split-bf16 MFMA ----------------
// r15 structure, but 32 rows x 128 cols per block, grid (512,2) = 1024 blocks
// = 4/CU (vs 2/CU): doubles resident blocks to hide the 2-barrier K-step
// drains (r5->r7 lesson). Per wave: 2 col-tiles x 2 row-tiles x 3 = 12
// MFMAs/K-step. A staging identical (verified conflict-free). Proj on y==0.
__global__ void __launch_bounds__(256) k_gemm_mfma(
        const float* __restrict__ x,
        const __bf16* __restrict__ Wh, const __bf16* __restrict__ Wl,
        const float* __restrict__ u_part, const float* __restrict__ bmlp,
        float* __restrict__ V, float* __restrict__ a, float* __restrict__ c) {
    __shared__ __bf16 Ah[32*40];    // 2.5 KB
    __shared__ __bf16 Al[32*40];
    __shared__ float4 ul[128];      // uq (64 float4) + uk (64 float4)
    __shared__ float pros[512];
    const int tid = threadIdx.x;
    const int wave = tid >> 6, lane = tid & 63;
    const int rowBase = blockIdx.x * 32;
    const int colBase = blockIdx.y * 128;
    const int quad = lane >> 4, l16 = lane & 15;
    const int srow = tid >> 3, skq = (tid & 7) * 4;   // staging: 8 thr/row
    const bool doproj = (blockIdx.y == 0);

    if (doproj && tid < 128) {
        float4 s = make_float4(0.f, 0.f, 0.f, 0.f);
        #pragma unroll
        for (int g = 0; g < 16; ++g) {
            float4 p = *(const float4*)(u_part + (size_t)g*512 + tid*4);
            s.x += p.x; s.y += p.y; s.z += p.z; s.w += p.w;
        }
        ul[tid] = s;
    }

    floatx4 acc[2][2];
    #pragma unroll
    for (int rt = 0; rt < 2; ++rt)
        #pragma unroll
        for (int ct = 0; ct < 2; ++ct)
            acc[rt][ct] = (floatx4){0.f, 0.f, 0.f, 0.f};
    float aq = 0.f, ak = 0.f;

    const float* xrow = x + (size_t)(rowBase + srow)*DD + skq;
    float4 xv = *(const float4*)xrow;          // prefetch tile 0
    for (int k0 = 0; k0 < DD; k0 += 32) {
        __syncthreads();
        __bf16 h0 = (__bf16)xv.x, h1 = (__bf16)xv.y, h2 = (__bf16)xv.z, h3 = (__bf16)xv.w;
        bf16x4 hv = {h0, h1, h2, h3};
        bf16x4 lv = {(__bf16)(xv.x - (float)h0), (__bf16)(xv.y - (float)h1),
                     (__bf16)(xv.z - (float)h2), (__bf16)(xv.w - (float)h3)};
        *(bf16x4*)&Ah[srow*40 + skq] = hv;
        *(bf16x4*)&Al[srow*40 + skq] = lv;
        if (doproj) {
            float4 q4 = ul[(k0 >> 2) + (tid & 7)];
            float4 k4 = ul[64 + (k0 >> 2) + (tid & 7)];
            aq = fmaf(xv.x, q4.x, fmaf(xv.y, q4.y, fmaf(xv.z, q4.z, fmaf(xv.w, q4.w, aq))));
            ak = fmaf(xv.x, k4.x, fmaf(xv.y, k4.y, fmaf(xv.z, k4.z, fmaf(xv.w, k4.w, ak))));
        }
        __syncthreads();
        if (k0 < DD - 32) xv = *(const float4*)(xrow + k0 + 32);   // overlaps MFMAs below
        bf16x8 ah[2], al[2];
        #pragma unroll
        for (int rt = 0; rt < 2; ++rt) {
            int m = rt*16 + l16;
            ah[rt] = *(bf16x8*)&Ah[m*40 + quad*8];
            al[rt] = *(bf16x8*)&Al[m*40 + quad*8];
        }
        #pragma unroll
        for (int ct = 0; ct < 2; ++ct) {
            int n = colBase + wave*32 + ct*16 + l16;
            bf16x8 bh = *(const bf16x8*)(Wh + (size_t)n*DD + k0 + quad*8);
            bf16x8 bl = *(const bf16x8*)(Wl + (size_t)n*DD + k0 + quad*8);
            #pragma unroll
            for (int rt = 0; rt < 2; ++rt) {
                acc[rt][ct] = __builtin_amdgcn_mfma_f32_16x16x32_bf16(ah[rt], bh, acc[rt][ct], 0, 0, 0);
                acc[rt][ct] = __builtin_amdgcn_mfma_f32_16x16x32_bf16(ah[rt], bl, acc[rt][ct], 0, 0, 0);
                acc[rt][ct] = __builtin_amdgcn_mfma_f32_16x16x32_bf16(al[rt], bh, acc[rt][ct], 0, 0, 0);
            }
        }
    }
    #pragma unroll
    for (int rt = 0; rt < 2; ++rt)
        #pragma unroll
        for (int ct = 0; ct < 2; ++ct)
            #pragma unroll
            for (int i = 0; i < 4; ++i) {
                int row = rowBase + rt*16 + quad*4 + i;
                int col = colBase + wave*32 + ct*16 + l16;
                V[(size_t)row*DD + col] = acc[rt][ct][i];
            }
    if (doproj) {
        __syncthreads();
        pros[tid] = aq;
        pros[256 + tid] = ak;
        __syncthreads();
        if (tid < 32) {
            float sa = 0.f, sc = 0.f;
            #pragma unroll
            for (int j = 0; j < 8; ++j) {
                sa += pros[tid*8 + j];
                sc += pros[256 + tid*8 + j];
            }
            a[rowBase + tid] = sa + bmlp[0];
            c[rowBase + tid] = sc;
        }
    }
}

// ---------------- K3: counting sort by value-bin + SE prefix ----------------
__global__ void __launch_bounds__(1024) k_sortish(const float* __restrict__ c,
        int* __restrict__ binstart_g, int* __restrict__ perm,
        float* __restrict__ c_sorted, float* __restrict__ e_sorted,
        float* __restrict__ SE, float* __restrict__ hdr) {
    __shared__ int   hist[NB];
    __shared__ float esl[LL];
    __shared__ float scrf[64];
    int b = blockIdx.x, tid = threadIdx.x;
    int wave = tid >> 6, lane = tid & 63;
    int* scri = (int*)scrf;

    float4 cv = ((const float4*)(c + (size_t)b*LL))[tid];
    float cw[4] = {cv.x, cv.y, cv.z, cv.w};
    float mn = fminf(fminf(cw[0],cw[1]), fminf(cw[2],cw[3]));
    float mx = fmaxf(fmaxf(cw[0],cw[1]), fmaxf(cw[2],cw[3]));
    #pragma unroll
    for (int off = 32; off > 0; off >>= 1) {
        mn = fminf(mn, __shfl_down(mn, off));
        mx = fmaxf(mx, __shfl_down(mx, off));
    }
    if (lane == 0) { scrf[wave] = mn; scrf[32 + wave] = mx; }
    __syncthreads();
    if (wave == 0) {
        float m = (lane < 16) ? scrf[lane]      :  3.4e38f;
        float M = (lane < 16) ? scrf[32 + lane] : -3.4e38f;
        #pragma unroll
        for (int off = 32; off > 0; off >>= 1) {
            m = fminf(m, __shfl_down(m, off));
            M = fmaxf(M, __shfl_down(M, off));
        }
        if (lane == 0) { scrf[0] = m; scrf[1] = M; }
    }
    __syncthreads();
    float cmin = scrf[0], cmax = scrf[1];
    float scale = (float)NB / fmaxf(cmax - cmin, 1e-20f);
    __syncthreads();

    ((int4*)hist)[tid] = make_int4(0,0,0,0);
    ((int4*)hist)[tid + 1024] = make_int4(0,0,0,0);
    __syncthreads();

    int bins[4];
    #pragma unroll
    for (int u = 0; u < 4; ++u) {
        int bi = (int)((cw[u] - cmin) * scale);
        bi = bi < 0 ? 0 : (bi > NB-1 ? NB-1 : bi);
        bins[u] = bi;
        atomicAdd(&hist[bi], 1);
    }
    __syncthreads();

    int loc[8]; int base = 0;
    #pragma unroll
    for (int j = 0; j < 8; ++j) { loc[j] = base; base += hist[tid*8 + j]; }
    int incl = base;
    #pragma unroll
    for (int off = 1; off < 64; off <<= 1) {
        int t = __shfl_up(incl, off);
        if (lane >= off) incl += t;
    }
    if (lane == 63) scri[wave] = incl;
    __syncthreads();
    if (wave == 0) {
        int v = (lane < 16) ? scri[lane] : 0;
        int s = v;
        #pragma unroll
        for (int off = 1; off < 16; off <<= 1) {
            int t = __shfl_up(s, off);
            if (lane >= off) s += t;
        }
        if (lane < 16) scri[lane] = s - v;
    }
    __syncthreads();
    int thread_excl = (incl - base) + scri[wave];
    __syncthreads();
    #pragma unroll
    for (int j = 0; j < 8; ++j) {
        int bs = thread_excl + loc[j];
        binstart_g[(size_t)b*(NB+2) + tid*8 + j] = bs;
        hist[tid*8 + j] = bs;
    }
    if (tid == 0) {
        binstart_g[(size_t)b*(NB+2) + NB]     = LL;
        binstart_g[(size_t)b*(NB+2) + NB + 1] = LL;
        hdr[b*2 + 0] = cmin;
        hdr[b*2 + 1] = scale;
    }
    __syncthreads();

    #pragma unroll
    for (int u = 0; u < 4; ++u) {
        int i = tid*4 + u;
        int r = atomicAdd(&hist[bins[u]], 1);
        float e = expf(cmin - cw[u]);
        perm[(size_t)b*LL + r] = i;
        c_sorted[(size_t)b*LL + r] = cw[u];
        e_sorted[(size_t)b*LL + r] = e;
        esl[r] = e;
    }
    __syncthreads();

    float le[4]; float s0 = 0.f;
    #pragma unroll
    for (int u = 0; u < 4; ++u) { le[u] = s0; s0 += esl[tid*4 + u]; }
    float fincl = s0;
    #pragma unroll
    for (int off = 1; off < 64; off <<= 1) {
        float t = __shfl_up(fincl, off);
        if (lane >= off) fincl += t;
    }
    if (lane == 63) scrf[wave] = fincl;
    __syncthreads();
    if (wave == 0) {
        float v = (lane < 16) ? scrf[lane] : 0.f;
        float s = v;
        #pragma unroll
        for (int off = 1; off < 16; off <<= 1) {
            float t = __shfl_up(s, off);
            if (lane >= off) s += t;
        }
        if (lane < 16) scrf[lane] = s - v;
    }
    __syncthreads();
    float texcl = (fincl - s0) + scrf[wave];
    #pragma unroll
    for (int u = 0; u < 4; ++u)
        SE[(size_t)b*(LL+1) + tid*4 + u] = texcl + le[u];
    if (tid == 1023) SE[(size_t)b*(LL+1) + LL] = texcl + s0;
}

// ---------------- K4: chunked exclusive prefix over V in rank order ----------------
__global__ void k_scan(const float* __restrict__ V, const int* __restrict__ perm,
        const float* __restrict__ e_sorted,
        float* __restrict__ Pl, float* __restrict__ Pel,
        float* __restrict__ Tp, float* __restrict__ Te) {
    int b = blockIdx.y, q = blockIdx.x;
    int d = threadIdx.x;
    __shared__ int pj[CHUNK];
    __shared__ float pe[CHUNK];
    if (d < CHUNK) {
        pj[d] = perm[(size_t)b*LL + q*CHUNK + d];
        pe[d] = e_sorted[(size_t)b*LL + q*CHUNK + d];
    }
    __syncthreads();
    float vr[CHUNK];
    #pragma unroll
    for (int r = 0; r < CHUNK; ++r)
        vr[r] = V[((size_t)b*LL + pj[r]) * DD + d];
    float acc = 0.f, acce = 0.f;
    size_t kb = (size_t)b*LL + (size_t)q*CHUNK;
    #pragma unroll
    for (int r = 0; r < CHUNK; ++r) {
        size_t o = (kb + r) * DD + d;
        Pl[o]  = acc;
        Pel[o] = acce;
        acc += vr[r];
        acce = fmaf(pe[r], vr[r], acce);
    }
    size_t to = ((size_t)b*NC + q) * DD + d;
    Tp[to] = acc;
    Te[to] = acce;
}

// ---------------- K5: chunk bases, parallel over (q, b) ----------------
__global__ void k_base(const float* __restrict__ Tp, const float* __restrict__ Te,
        float* __restrict__ baseP, float* __restrict__ basePe) {
    int q = blockIdx.x, b = blockIdx.y, d = threadIdx.x;
    float acc = 0.f, acce = 0.f;
    #pragma unroll 8
    for (int i = 0; i < q; ++i) {
        size_t ti = ((size_t)b*NC + i) * DD + d;
        acc += Tp[ti]; acce += Te[ti];
    }
    size_t o = ((size_t)b*(NC+1) + q) * DD + d;
    baseP[o] = acc; basePe[o] = acce;
}

// ---------------- K6: per-row output, O(1) bin lookup + exact boundary fix ----------------
__global__ void k_out(const float* __restrict__ a, const float* __restrict__ hdr,
                      const int* __restrict__ binstart,
                      const float* __restrict__ c_sorted, const float* __restrict__ e_sorted,
                      const int* __restrict__ perm, const float* __restrict__ V,
                      const float* __restrict__ SE,
                      const float* __restrict__ Pl, const float* __restrict__ Pel,
                      const float* __restrict__ baseP, const float* __restrict__ basePe,
                      float* __restrict__ out) {
    int row = blockIdx.x * 4 + (threadIdx.x >> 6);
    int lane = threadIdx.x & 63;
    int b = row >> 12;
    float ai = a[row];
    float cmin = hdr[b*2 + 0], scale = hdr[b*2 + 1];
    float t = (ai - cmin) * scale;
    int ib = t < 0.f ? 0 : (t >= (float)NB ? NB : (int)t);
    int k    = binstart[(size_t)b*(NB+2) + ib];
    int kend = binstart[(size_t)b*(NB+2) + ib + 1];
    float alpha = expf(cmin - ai);
    float Z = fmaf(alpha, (float)(LL - k), SE[(size_t)b*(LL+1) + k]);
    size_t db = (size_t)lane * 4;
    size_t totoff = ((size_t)b * (NC+1) + NC) * DD + db;
    float4 ptot  = *(const float4*)(baseP  + totoff);
    float4 pk, pek;
    if (k < LL) {
        int q = k >> 5;
        size_t po = ((size_t)b * LL + k) * DD + db;
        size_t bo = ((size_t)b * (NC+1) + q) * DD + db;
        float4 pl = *(const float4*)(Pl    + po);
        float4 bp = *(const float4*)(baseP + bo);
        float4 pe = *(const float4*)(Pel    + po);
        float4 be = *(const float4*)(basePe + bo);
        pk.x = pl.x + bp.x; pk.y = pl.y + bp.y; pk.z = pl.z + bp.z; pk.w = pl.w + bp.w;
        pek.x = pe.x + be.x; pek.y = pe.y + be.y; pek.z = pe.z + be.z; pek.w = pe.w + be.w;
    } else {
        pk = ptot;
        pek = *(const float4*)(basePe + totoff);
    }
    float4 num;
    num.x = fmaf(alpha, ptot.x - pk.x, pek.x);
    num.y = fmaf(alpha, ptot.y - pk.y, pek.y);
    num.z = fmaf(alpha, ptot.z - pk.z, pek.z);
    num.w = fmaf(alpha, ptot.w - pk.w, pek.w);
    for (int r = k; r < kend; ++r) {
        float cr = c_sorted[(size_t)b*LL + r];
        if (cr < ai) {
            float w = e_sorted[(size_t)b*LL + r] - alpha;
            int j = perm[(size_t)b*LL + r];
            float4 v = *(const float4*)(V + ((size_t)b*LL + j) * DD + db);
            num.x = fmaf(w, v.x, num.x);
            num.y = fmaf(w, v.y, num.y);
            num.z = fmaf(w, v.z, num.z);
            num.w = fmaf(w, v.w, num.w);
            Z += w;
        }
    }
    float invZ = 1.f / Z;
    float4 o;
    o.x = num.x * invZ; o.y = num.y * invZ; o.z = num.z * invZ; o.w = num.w * invZ;
    *(float4*)(out + (size_t)row * DD + db) = o;
}

extern "C" void kernel_launch(void* const* d_in, const int* in_sizes, int n_in,
                              void* d_out, int out_size, void* d_ws, size_t ws_size,
                              hipStream_t stream) {
    const float* x  = (const float*)d_in[0];
    const float* Wq = (const float*)d_in[1];
    const float* Wk = (const float*)d_in[2];
    const float* Wv = (const float*)d_in[3];
    const float* wm = (const float*)d_in[4];
    const float* bm = (const float*)d_in[5];
    float* out = (float*)d_out;
    float* ws = (float*)d_ws;

    size_t off = 0;
    auto alloc = [&](size_t n) {      // n in floats
        float* p = ws + off;
        off += (n + 255) & ~(size_t)255;
        return p;
    };
    float* u_part   = alloc(16*512);
    float* a        = alloc(NROWS);
    float* c        = alloc(NROWS);
    float* c_sorted = alloc(NROWS);
    float* e_sorted = alloc(NROWS);
    float* SE       = alloc((size_t)BB*(LL+1));
    int*   perm     = (int*)alloc(NROWS);
    int*   binstart = (int*)alloc((size_t)BB*(NB+2));
    float* hdr      = alloc(2*BB);
    float* V        = alloc((size_t)NROWS*DD);
    float* Pl       = alloc((size_t)NROWS*DD);
    float* Pel      = alloc((size_t)NROWS*DD);
    float* Tp       = alloc((size_t)BB*NC*DD);
    float* Te       = alloc((size_t)BB*NC*DD);
    float* baseP    = alloc((size_t)BB*(NC+1)*DD);
    float* basePe   = alloc((size_t)BB*(NC+1)*DD);
    __bf16* Wh      = (__bf16*)alloc((size_t)DD*DD/2);
    __bf16* Wl      = (__bf16*)alloc((size_t)DD*DD/2);

    hipLaunchKernelGGL(k_prep, dim3(16), dim3(DD), 0, stream, Wq, Wk, Wv, wm, u_part, Wh, Wl);
    hipLaunchKernelGGL(k_gemm_mfma, dim3(NROWS/32, 2), dim3(256), 0, stream,
                       x, Wh, Wl, u_part, bm, V, a, c);
    hipLaunchKernelGGL(k_sortish, dim3(BB), dim3(1024), 0, stream,
                       c, binstart, perm, c_sorted, e_sorted, SE, hdr);
    hipLaunchKernelGGL(k_scan, dim3(NC, BB), dim3(DD), 0, stream, V, perm, e_sorted, Pl, Pel, Tp, Te);
    hipLaunchKernelGGL(k_base, dim3(NC+1, BB), dim3(DD), 0, stream, Tp, Te, baseP, basePe);
    hipLaunchKernelGGL(k_out, dim3(NROWS/4), dim3(256), 0, stream,
                       a, hdr, binstart, c_sorted, e_sorted, perm, V,
                       SE, Pl, Pel, baseP, basePe, out);
}

// Round 19
// 135.385 us; speedup vs baseline: 1.0807x; 1.0001x over previous
//
#include <hip/hip_runtime.h>
#include <math.h>

#define BB 4
#define LL 4096
#define DD 256
#define NROWS (BB*LL)      // 16384
#define CHUNK 32
#define NC (LL/CHUNK)      // 128
#define NB 8192            // counting-sort bins

typedef __bf16 bf16x8 __attribute__((ext_vector_type(8)));
typedef __bf16 bf16x4 __attribute__((ext_vector_type(4)));
typedef float floatx4 __attribute__((ext_vector_type(4)));

// ---------------- K1: partial u = {Wq^T w, Wk^T w} (no atomics/memset) + split Wv ----------------
__global__ void k_prep(const float* __restrict__ Wq, const float* __restrict__ Wk,
                       const float* __restrict__ Wv, const float* __restrict__ w,
                       float* __restrict__ u_part,
                       __bf16* __restrict__ Wh, __bf16* __restrict__ Wl) {
    __shared__ float wl[16];
    int d = threadIdx.x;
    int e0 = blockIdx.x * 16;
    if (d < 16) wl[d] = w[e0 + d];
    __syncthreads();
    float aq = 0.f, ak = 0.f;
    #pragma unroll
    for (int j = 0; j < 16; ++j) {
        float we = wl[j];
        aq = fmaf(Wq[(size_t)(e0 + j)*DD + d], we, aq);
        ak = fmaf(Wk[(size_t)(e0 + j)*DD + d], we, ak);
        float wv = Wv[(size_t)(e0 + j)*DD + d];
        __bf16 h = (__bf16)wv;
        Wh[(size_t)(e0 + j)*DD + d] = h;
        Wl[(size_t)(e0 + j)*DD + d] = (__bf16)(wv - (float)h);
    }
    u_part[(size_t)blockIdx.x*512 + d]       = aq;
    u_part[(size_t)blockIdx.x*512 + DD + d]  = ak;
}

// ---------------- K2: V = x @ Wv^T via split-bf16 MFMA ----------------
// Single-barrier double-buffered A staging (r17), with the r17 BUG FIXED:
// __syncthreads() after ul staging, BEFORE the prologue proj read of ul.
// (r17 read ul unsynchronized -> NaN. Buffer hazards themselves are sound:
// reads(buf[c], pre-barrier-t) vs writes(buf[c], post-barrier-t at iter t+1)
// and writes(buf[c^1], pre-barrier-t) vs reads(buf[c^1], post-barrier-t at
// iter t+1) are each separated by barrier t.)
__global__ void __launch_bounds__(256) k_gemm_mfma(
        const float* __restrict__ x,
        const __bf16* __restrict__ Wh, const __bf16* __restrict__ Wl,
        const float* __restrict__ u_part, const float* __restrict__ bmlp,
        float* __restrict__ V, float* __restrict__ a, float* __restrict__ c) {
    __shared__ __bf16 Ah[2][32*40];    // 2x2.5 KB
    __shared__ __bf16 Al[2][32*40];
    __shared__ float4 ul[128];         // uq (64 float4) + uk (64 float4)
    __shared__ float pros[512];
    const int tid = threadIdx.x;
    const int wave = tid >> 6, lane = tid & 63;
    const int rowBase = blockIdx.x * 32;
    const int colBase = blockIdx.y * 128;
    const int quad = lane >> 4, l16 = lane & 15;
    const int srow = tid >> 3, skq = (tid & 7) * 4;   // staging: 8 thr/row
    const bool doproj = (blockIdx.y == 0);

    if (doproj && tid < 128) {
        float4 s = make_float4(0.f, 0.f, 0.f, 0.f);
        #pragma unroll
        for (int g = 0; g < 16; ++g) {
            float4 p = *(const float4*)(u_part + (size_t)g*512 + tid*4);
            s.x += p.x; s.y += p.y; s.z += p.z; s.w += p.w;
        }
        ul[tid] = s;
    }
    __syncthreads();     // *** r17 fix: publish ul before prologue proj reads ***

    floatx4 acc[2][2];
    #pragma unroll
    for (int rt = 0; rt < 2; ++rt)
        #pragma unroll
        for (int ct = 0; ct < 2; ++ct)
            acc[rt][ct] = (floatx4){0.f, 0.f, 0.f, 0.f};
    float aq = 0.f, ak = 0.f;

    const float* xrow = x + (size_t)(rowBase + srow)*DD + skq;

    // prologue: stage + proj tile 0 into buf 0
    {
        float4 xv = *(const float4*)xrow;
        __bf16 h0 = (__bf16)xv.x, h1 = (__bf16)xv.y, h2 = (__bf16)xv.z, h3 = (__bf16)xv.w;
        bf16x4 hv = {h0, h1, h2, h3};
        bf16x4 lv = {(__bf16)(xv.x - (float)h0), (__bf16)(xv.y - (float)h1),
                     (__bf16)(xv.z - (float)h2), (__bf16)(xv.w - (float)h3)};
        *(bf16x4*)&Ah[0][srow*40 + skq] = hv;
        *(bf16x4*)&Al[0][srow*40 + skq] = lv;
        if (doproj) {
            float4 q4 = ul[(tid & 7)];
            float4 k4 = ul[64 + (tid & 7)];
            aq = fmaf(xv.x, q4.x, fmaf(xv.y, q4.y, fmaf(xv.z, q4.z, fmaf(xv.w, q4.w, aq))));
            ak = fmaf(xv.x, k4.x, fmaf(xv.y, k4.y, fmaf(xv.z, k4.z, fmaf(xv.w, k4.w, ak))));
        }
    }
    __syncthreads();

    for (int t = 0; t < 8; ++t) {
        const int k0 = t * 32;
        const int cur = t & 1;
        // prefetch next x tile
        float4 xv;
        if (t < 7) xv = *(const float4*)(xrow + k0 + 32);
        // fragment reads of buf[cur] -> registers (all LDS reads up front)
        bf16x8 ah[2], al[2];
        #pragma unroll
        for (int rt = 0; rt < 2; ++rt) {
            int m = rt*16 + l16;
            ah[rt] = *(bf16x8*)&Ah[cur][m*40 + quad*8];
            al[rt] = *(bf16x8*)&Al[cur][m*40 + quad*8];
        }
        // stage tile t+1 into the other buffer (+ proj on it)
        if (t < 7) {
            __bf16 h0 = (__bf16)xv.x, h1 = (__bf16)xv.y, h2 = (__bf16)xv.z, h3 = (__bf16)xv.w;
            bf16x4 hv = {h0, h1, h2, h3};
            bf16x4 lv = {(__bf16)(xv.x - (float)h0), (__bf16)(xv.y - (float)h1),
                         (__bf16)(xv.z - (float)h2), (__bf16)(xv.w - (float)h3)};
            *(bf16x4*)&Ah[cur^1][srow*40 + skq] = hv;
            *(bf16x4*)&Al[cur^1][srow*40 + skq] = lv;
            if (doproj) {
                float4 q4 = ul[((k0 + 32) >> 2) + (tid & 7)];
                float4 k4 = ul[64 + ((k0 + 32) >> 2) + (tid & 7)];
                aq = fmaf(xv.x, q4.x, fmaf(xv.y, q4.y, fmaf(xv.z, q4.z, fmaf(xv.w, q4.w, aq))));
                ak = fmaf(xv.x, k4.x, fmaf(xv.y, k4.y, fmaf(xv.z, k4.z, fmaf(xv.w, k4.w, ak))));
            }
        }
        __syncthreads();   // the ONE barrier per K-step
        #pragma unroll
        for (int ct = 0; ct < 2; ++ct) {
            int n = colBase + wave*32 + ct*16 + l16;
            bf16x8 bh = *(const bf16x8*)(Wh + (size_t)n*DD + k0 + quad*8);
            bf16x8 bl = *(const bf16x8*)(Wl + (size_t)n*DD + k0 + quad*8);
            #pragma unroll
            for (int rt = 0; rt < 2; ++rt) {
                acc[rt][ct] = __builtin_amdgcn_mfma_f32_16x16x32_bf16(ah[rt], bh, acc[rt][ct], 0, 0, 0);
                acc[rt][ct] = __builtin_amdgcn_mfma_f32_16x16x32_bf16(ah[rt], bl, acc[rt][ct], 0, 0, 0);
                acc[rt][ct] = __builtin_amdgcn_mfma_f32_16x16x32_bf16(al[rt], bh, acc[rt][ct], 0, 0, 0);
            }
        }
    }
    #pragma unroll
    for (int rt = 0; rt < 2; ++rt)
        #pragma unroll
        for (int ct = 0; ct < 2; ++ct)
            #pragma unroll
            for (int i = 0; i < 4; ++i) {
                int row = rowBase + rt*16 + quad*4 + i;
                int col = colBase + wave*32 + ct*16 + l16;
                V[(size_t)row*DD + col] = acc[rt][ct][i];
            }
    if (doproj) {
        __syncthreads();
        pros[tid] = aq;
        pros[256 + tid] = ak;
        __syncthreads();
        if (tid < 32) {
            float sa = 0.f, sc = 0.f;
            #pragma unroll
            for (int j = 0; j < 8; ++j) {
                sa += pros[tid*8 + j];
                sc += pros[256 + tid*8 + j];
            }
            a[rowBase + tid] = sa + bmlp[0];
            c[rowBase + tid] = sc;
        }
    }
}

// ---------------- K3: counting sort by value-bin + SE prefix ----------------
__global__ void __launch_bounds__(1024) k_sortish(const float* __restrict__ c,
        int* __restrict__ binstart_g, int* __restrict__ perm,
        float* __restrict__ c_sorted, float* __restrict__ e_sorted,
        float* __restrict__ SE, float* __restrict__ hdr) {
    __shared__ int   hist[NB];
    __shared__ float esl[LL];
    __shared__ float scrf[64];
    int b = blockIdx.x, tid = threadIdx.x;
    int wave = tid >> 6, lane = tid & 63;
    int* scri = (int*)scrf;

    float4 cv = ((const float4*)(c + (size_t)b*LL))[tid];
    float cw[4] = {cv.x, cv.y, cv.z, cv.w};
    float mn = fminf(fminf(cw[0],cw[1]), fminf(cw[2],cw[3]));
    float mx = fmaxf(fmaxf(cw[0],cw[1]), fmaxf(cw[2],cw[3]));
    #pragma unroll
    for (int off = 32; off > 0; off >>= 1) {
        mn = fminf(mn, __shfl_down(mn, off));
        mx = fmaxf(mx, __shfl_down(mx, off));
    }
    if (lane == 0) { scrf[wave] = mn; scrf[32 + wave] = mx; }
    __syncthreads();
    if (wave == 0) {
        float m = (lane < 16) ? scrf[lane]      :  3.4e38f;
        float M = (lane < 16) ? scrf[32 + lane] : -3.4e38f;
        #pragma unroll
        for (int off = 32; off > 0; off >>= 1) {
            m = fminf(m, __shfl_down(m, off));
            M = fmaxf(M, __shfl_down(M, off));
        }
        if (lane == 0) { scrf[0] = m; scrf[1] = M; }
    }
    __syncthreads();
    float cmin = scrf[0], cmax = scrf[1];
    float scale = (float)NB / fmaxf(cmax - cmin, 1e-20f);
    __syncthreads();

    ((int4*)hist)[tid] = make_int4(0,0,0,0);
    ((int4*)hist)[tid + 1024] = make_int4(0,0,0,0);
    __syncthreads();

    int bins[4];
    #pragma unroll
    for (int u = 0; u < 4; ++u) {
        int bi = (int)((cw[u] - cmin) * scale);
        bi = bi < 0 ? 0 : (bi > NB-1 ? NB-1 : bi);
        bins[u] = bi;
        atomicAdd(&hist[bi], 1);
    }
    __syncthreads();

    int loc[8]; int base = 0;
    #pragma unroll
    for (int j = 0; j < 8; ++j) { loc[j] = base; base += hist[tid*8 + j]; }
    int incl = base;
    #pragma unroll
    for (int off = 1; off < 64; off <<= 1) {
        int t = __shfl_up(incl, off);
        if (lane >= off) incl += t;
    }
    if (lane == 63) scri[wave] = incl;
    __syncthreads();
    if (wave == 0) {
        int v = (lane < 16) ? scri[lane] : 0;
        int s = v;
        #pragma unroll
        for (int off = 1; off < 16; off <<= 1) {
            int t = __shfl_up(s, off);
            if (lane >= off) s += t;
        }
        if (lane < 16) scri[lane] = s - v;
    }
    __syncthreads();
    int thread_excl = (incl - base) + scri[wave];
    __syncthreads();
    #pragma unroll
    for (int j = 0; j < 8; ++j) {
        int bs = thread_excl + loc[j];
        binstart_g[(size_t)b*(NB+2) + tid*8 + j] = bs;
        hist[tid*8 + j] = bs;
    }
    if (tid == 0) {
        binstart_g[(size_t)b*(NB+2) + NB]     = LL;
        binstart_g[(size_t)b*(NB+2) + NB + 1] = LL;
        hdr[b*2 + 0] = cmin;
        hdr[b*2 + 1] = scale;
    }
    __syncthreads();

    #pragma unroll
    for (int u = 0; u < 4; ++u) {
        int i = tid*4 + u;
        int r = atomicAdd(&hist[bins[u]], 1);
        float e = expf(cmin - cw[u]);
        perm[(size_t)b*LL + r] = i;
        c_sorted[(size_t)b*LL + r] = cw[u];
        e_sorted[(size_t)b*LL + r] = e;
        esl[r] = e;
    }
    __syncthreads();

    float le[4]; float s0 = 0.f;
    #pragma unroll
    for (int u = 0; u < 4; ++u) { le[u] = s0; s0 += esl[tid*4 + u]; }
    float fincl = s0;
    #pragma unroll
    for (int off = 1; off < 64; off <<= 1) {
        float t = __shfl_up(fincl, off);
        if (lane >= off) fincl += t;
    }
    if (lane == 63) scrf[wave] = fincl;
    __syncthreads();
    if (wave == 0) {
        float v = (lane < 16) ? scrf[lane] : 0.f;
        float s = v;
        #pragma unroll
        for (int off = 1; off < 16; off <<= 1) {
            float t = __shfl_up(s, off);
            if (lane >= off) s += t;
        }
        if (lane < 16) scrf[lane] = s - v;
    }
    __syncthreads();
    float texcl = (fincl - s0) + scrf[wave];
    #pragma unroll
    for (int u = 0; u < 4; ++u)
        SE[(size_t)b*(LL+1) + tid*4 + u] = texcl + le[u];
    if (tid == 1023) SE[(size_t)b*(LL+1) + LL] = texcl + s0;
}

// ---------------- K4: chunked exclusive prefix over V in rank order ----------------
__global__ void k_scan(const float* __restrict__ V, const int* __restrict__ perm,
        const float* __restrict__ e_sorted,
        float* __restrict__ Pl, float* __restrict__ Pel,
        float* __restrict__ Tp, float* __restrict__ Te) {
    int b = blockIdx.y, q = blockIdx.x;
    int d = threadIdx.x;
    __shared__ int pj[CHUNK];
    __shared__ float pe[CHUNK];
    if (d < CHUNK) {
        pj[d] = perm[(size_t)b*LL + q*CHUNK + d];
        pe[d] = e_sorted[(size_t)b*LL + q*CHUNK + d];
    }
    __syncthreads();
    float vr[CHUNK];
    #pragma unroll
    for (int r = 0; r < CHUNK; ++r)
        vr[r] = V[((size_t)b*LL + pj[r]) * DD + d];
    float acc = 0.f, acce = 0.f;
    size_t kb = (size_t)b*LL + (size_t)q*CHUNK;
    #pragma unroll
    for (int r = 0; r < CHUNK; ++r) {
        size_t o = (kb + r) * DD + d;
        Pl[o]  = acc;
        Pel[o] = acce;
        acc += vr[r];
        acce = fmaf(pe[r], vr[r], acce);
    }
    size_t to = ((size_t)b*NC + q) * DD + d;
    Tp[to] = acc;
    Te[to] = acce;
}

// ---------------- K5: chunk bases, parallel over (q, b) ----------------
__global__ void k_base(const float* __restrict__ Tp, const float* __restrict__ Te,
        float* __restrict__ baseP, float* __restrict__ basePe) {
    int q = blockIdx.x, b = blockIdx.y, d = threadIdx.x;
    float acc = 0.f, acce = 0.f;
    #pragma unroll 8
    for (int i = 0; i < q; ++i) {
        size_t ti = ((size_t)b*NC + i) * DD + d;
        acc += Tp[ti]; acce += Te[ti];
    }
    size_t o = ((size_t)b*(NC+1) + q) * DD + d;
    baseP[o] = acc; basePe[o] = acce;
}

// ---------------- K6: per-row output, O(1) bin lookup + exact boundary fix ----------------
__global__ void k_out(const float* __restrict__ a, const float* __restrict__ hdr,
                      const int* __restrict__ binstart,
                      const float* __restrict__ c_sorted, const float* __restrict__ e_sorted,
                      const int* __restrict__ perm, const float* __restrict__ V,
                      const float* __restrict__ SE,
                      const float* __restrict__ Pl, const float* __restrict__ Pel,
                      const float* __restrict__ baseP, const float* __restrict__ basePe,
                      float* __restrict__ out) {
    int row = blockIdx.x * 4 + (threadIdx.x >> 6);
    int lane = threadIdx.x & 63;
    int b = row >> 12;
    float ai = a[row];
    float cmin = hdr[b*2 + 0], scale = hdr[b*2 + 1];
    float t = (ai - cmin) * scale;
    int ib = t < 0.f ? 0 : (t >= (float)NB ? NB : (int)t);
    int k    = binstart[(size_t)b*(NB+2) + ib];
    int kend = binstart[(size_t)b*(NB+2) + ib + 1];
    float alpha = expf(cmin - ai);
    float Z = fmaf(alpha, (float)(LL - k), SE[(size_t)b*(LL+1) + k]);
    size_t db = (size_t)lane * 4;
    size_t totoff = ((size_t)b * (NC+1) + NC) * DD + db;
    float4 ptot  = *(const float4*)(baseP  + totoff);
    float4 pk, pek;
    if (k < LL) {
        int q = k >> 5;
        size_t po = ((size_t)b * LL + k) * DD + db;
        size_t bo = ((size_t)b * (NC+1) + q) * DD + db;
        float4 pl = *(const float4*)(Pl    + po);
        float4 bp = *(const float4*)(baseP + bo);
        float4 pe = *(const float4*)(Pel    + po);
        float4 be = *(const float4*)(basePe + bo);
        pk.x = pl.x + bp.x; pk.y = pl.y + bp.y; pk.z = pl.z + bp.z; pk.w = pl.w + bp.w;
        pek.x = pe.x + be.x; pek.y = pe.y + be.y; pek.z = pe.z + be.z; pek.w = pe.w + be.w;
    } else {
        pk = ptot;
        pek = *(const float4*)(basePe + totoff);
    }
    float4 num;
    num.x = fmaf(alpha, ptot.x - pk.x, pek.x);
    num.y = fmaf(alpha, ptot.y - pk.y, pek.y);
    num.z = fmaf(alpha, ptot.z - pk.z, pek.z);
    num.w = fmaf(alpha, ptot.w - pk.w, pek.w);
    for (int r = k; r < kend; ++r) {
        float cr = c_sorted[(size_t)b*LL + r];
        if (cr < ai) {
            float w = e_sorted[(size_t)b*LL + r] - alpha;
            int j = perm[(size_t)b*LL + r];
            float4 v = *(const float4*)(V + ((size_t)b*LL + j) * DD + db);
            num.x = fmaf(w, v.x, num.x);
            num.y = fmaf(w, v.y, num.y);
            num.z = fmaf(w, v.z, num.z);
            num.w = fmaf(w, v.w, num.w);
            Z += w;
        }
    }
    float invZ = 1.f / Z;
    float4 o;
    o.x = num.x * invZ; o.y = num.y * invZ; o.z = num.z * invZ; o.w = num.w * invZ;
    *(float4*)(out + (size_t)row * DD + db) = o;
}

extern "C" void kernel_launch(void* const* d_in, const int* in_sizes, int n_in,
                              void* d_out, int out_size, void* d_ws, size_t ws_size,
                              hipStream_t stream) {
    const float* x  = (const float*)d_in[0];
    const float* Wq = (const float*)d_in[1];
    const float* Wk = (const float*)d_in[2];
    const float* Wv = (const float*)d_in[3];
    const float* wm = (const float*)d_in[4];
    const float* bm = (const float*)d_in[5];
    float* out = (float*)d_out;
    float* ws = (float*)d_ws;

    size_t off = 0;
    auto alloc = [&](size_t n) {      // n in floats
        float* p = ws + off;
        off += (n + 255) & ~(size_t)255;
        return p;
    };
    float* u_part   = alloc(16*512);
    float* a        = alloc(NROWS);
    float* c        = alloc(NROWS);
    float* c_sorted = alloc(NROWS);
    float* e_sorted = alloc(NROWS);
    float* SE       = alloc((size_t)BB*(LL+1));
    int*   perm     = (int*)alloc(NROWS);
    int*   binstart = (int*)alloc((size_t)BB*(NB+2));
    float* hdr      = alloc(2*BB);
    float* V        = alloc((size_t)NROWS*DD);
    float* Pl       = alloc((size_t)NROWS*DD);
    float* Pel      = alloc((size_t)NROWS*DD);
    float* Tp       = alloc((size_t)BB*NC*DD);
    float* Te       = alloc((size_t)BB*NC*DD);
    float* baseP    = alloc((size_t)BB*(NC+1)*DD);
    float* basePe   = alloc((size_t)BB*(NC+1)*DD);
    __bf16* Wh      = (__bf16*)alloc((size_t)DD*DD/2);
    __bf16* Wl      = (__bf16*)alloc((size_t)DD*DD/2);

    hipLaunchKernelGGL(k_prep, dim3(16), dim3(DD), 0, stream, Wq, Wk, Wv, wm, u_part, Wh, Wl);
    hipLaunchKernelGGL(k_gemm_mfma, dim3(NROWS/32, 2), dim3(256), 0, stream,
                       x, Wh, Wl, u_part, bm, V, a, c);
    hipLaunchKernelGGL(k_sortish, dim3(BB), dim3(1024), 0, stream,
                       c, binstart, perm, c_sorted, e_sorted, SE, hdr);
    hipLaunchKernelGGL(k_scan, dim3(NC, BB), dim3(DD), 0, stream, V, perm, e_sorted, Pl, Pel, Tp, Te);
    hipLaunchKernelGGL(k_base, dim3(NC+1, BB), dim3(DD), 0, stream, Tp, Te, baseP, basePe);
    hipLaunchKernelGGL(k_out, dim3(NROWS/4), dim3(256), 0, stream,
                       a, hdr, binstart, c_sorted, e_sorted, perm, V,
                       SE, Pl, Pel, baseP, basePe, out);
}